// Round 6
// baseline (450.064 us; speedup 1.0000x reference)
//
#include <hip/hip_runtime.h>
#include <hip/hip_fp16.h>
#include <math.h>

#define FIXLEN 30.0f
#define BETA   0.25f

typedef unsigned short u16;
typedef unsigned int   u32;
typedef unsigned long long u64;
typedef _Float16 half8 __attribute__((ext_vector_type(8)));
typedef float    f32x4 __attribute__((ext_vector_type(4)));

// ---------------- ws layout (bytes) ----------------
#define CST_OFF    512       // f[16]: 0=scale,1=inv_s,2=EPS2,3=maxNrm,4=T_cut
#define CNT_OFF    576       // i[2]: 0=refine cnt, 1=cand cnt
#define DIFF_OFF   1024      // f[256]
#define ZMAX_OFF   2048      // f[1024]
#define EMAXL_OFF  6144      // f[2048]
#define EMAXE_OFF  14336     // f[2048]
#define E2_OFF     22528     // f[16384]
#define BESTN_OFF  88064     // i[16384]
#define LIST_OFF   153600    // i[16384]
#define PV1_OFF    219136    // u64[16384]
#define CIDX_OFF   481280    // i32[16384] candidate index list
#define CE2_OFF    612352    // f32[16384] candidate e2*inv_s (padded 3e37)
#define PVB2_OFF   1267712   // f[16384]
#define ZS_OFF     1398784   // f[4*16384] per-token z^2 partials (4 c-planes)
#define ZH_OFF     1792000   // half[16384*256]
#define EHC_OFF    10180608  // half[16384*256] gathered candidate plane

__device__ inline u32 fkey(float d) {
    u32 b = __float_as_uint(d);
    return (b & 0x80000000u) ? ~b : (b | 0x80000000u);
}
__device__ inline float fdec(u32 k) {
    u32 b = (k & 0x80000000u) ? (k & 0x7FFFFFFFu) : ~k;
    return __uint_as_float(b);
}
__device__ inline void gl_lds16(const void* g, void* l) {
    __builtin_amdgcn_global_load_lds(
        (const __attribute__((address_space(1))) unsigned int*)g,
        (__attribute__((address_space(3))) unsigned int*)l, 16, 0, 0);
}

// ---------------- K1: emb -> e2 + residual-norm maxes (no fp16 plane stored) ----------------
__global__ void k_split_e(const float* __restrict__ emb, float* __restrict__ e2,
                          float* __restrict__ emaxl, float* __restrict__ emaxe) {
    int gidx = blockIdx.x * 256 + threadIdx.x;   // grid = 2048
    int n = gidx >> 5;
    int c8 = (gidx & 31) * 8;
    const float* ep = emb + (size_t)n * 256 + c8;
    float4 v0 = *(const float4*)ep;
    float4 v1 = *(const float4*)(ep + 4);
    float vv[8] = {v0.x, v0.y, v0.z, v0.w, v1.x, v1.y, v1.z, v1.w};
    float s2 = 0.f, r2 = 0.f;
    #pragma unroll
    for (int k = 0; k < 8; ++k) {
        __half h = __float2half(vv[k]);
        float r = vv[k] - __half2float(h);
        s2 = fmaf(vv[k], vv[k], s2);
        r2 = fmaf(r, r, r2);
    }
    #pragma unroll
    for (int off = 16; off > 0; off >>= 1) {
        s2 += __shfl_down(s2, off, 32);
        r2 += __shfl_down(r2, off, 32);
    }
    __shared__ float L1[8], L2[8];
    if ((threadIdx.x & 31) == 0) {
        e2[n] = s2;
        L1[threadIdx.x >> 5] = r2;
        L2[threadIdx.x >> 5] = s2;
    }
    __syncthreads();
    if (threadIdx.x == 0) {
        float a = 0.f, bmax = 0.f;
        #pragma unroll
        for (int i = 0; i < 8; ++i) { a = fmaxf(a, L1[i]); bmax = fmaxf(bmax, L2[i]); }
        emaxl[blockIdx.x] = a;
        emaxe[blockIdx.x] = bmax;
    }
}

// ---------------- K2: z -> fp16(-2*z/30) plane (transpose) + residual max + z^2 partials ------
__global__ void k_split_z(const float* __restrict__ z, u16* __restrict__ zh,
                          float* __restrict__ zmax_part, float* __restrict__ zsumP) {
    int bi = blockIdx.x;                     // grid = 1024
    int b = bi >> 6, rest = bi & 63;
    int c0 = (rest >> 4) * 64, s0 = (rest & 15) * 64;
    __shared__ float ld[64][65];
    __shared__ float red2[64][4];
    __shared__ float redz[64][4];
    __shared__ float rmax[64];
    int tid = threadIdx.x;
    #pragma unroll
    for (int p = 0; p < 16; ++p) {
        int idx = p * 256 + tid;
        int cc = idx >> 6, ss = idx & 63;
        ld[cc][ss] = z[(size_t)b * 262144 + (size_t)(c0 + cc) * 1024 + s0 + ss];
    }
    __syncthreads();
    int ss2 = tid >> 2, cq = tid & 3;
    int t = b * 1024 + s0 + ss2;
    float r2 = 0.f, zacc = 0.f;
    u32 pk[8];
    #pragma unroll
    for (int k = 0; k < 8; ++k) pk[k] = 0;
    #pragma unroll
    for (int j = 0; j < 16; ++j) {
        float raw = ld[cq * 16 + j][ss2];
        zacc = fmaf(raw, raw, zacc);
        float v = raw * (1.0f / 30.0f);
        __half h = __float2half(v);
        float vh = __half2float(h);
        float r = v - vh;
        r2 = fmaf(r, r, r2);
        __half hs = __float2half(-2.0f * vh);   // exact power-of-2 scale
        pk[j >> 1] |= ((u32)__half_as_ushort(hs)) << ((j & 1) * 16);
    }
    u16* dst = zh + (size_t)t * 256 + c0 + cq * 16;
    *(uint4*)dst = make_uint4(pk[0], pk[1], pk[2], pk[3]);
    *(uint4*)(dst + 8) = make_uint4(pk[4], pk[5], pk[6], pk[7]);
    red2[ss2][cq] = r2;
    redz[ss2][cq] = zacc;
    __syncthreads();
    if (tid < 64) {
        rmax[tid] = red2[tid][0] + red2[tid][1] + red2[tid][2] + red2[tid][3];
        zsumP[(size_t)(rest >> 4) * 16384 + b * 1024 + s0 + tid] =
            redz[tid][0] + redz[tid][1] + redz[tid][2] + redz[tid][3];
    }
    __syncthreads();
    for (int off = 32; off > 0; off >>= 1) {
        if (tid < off) rmax[tid] = fmaxf(rmax[tid], rmax[tid + off]);
        __syncthreads();
    }
    if (tid == 0) zmax_part[bi] = rmax[0];
}

// ---------------- K3: scalars: scale + EPS2 + T_cut (screen threshold) + counter reset --------
__global__ void k_scalars(const float* __restrict__ zsumP, const float* __restrict__ zmax_part,
                          const float* __restrict__ emaxl, const float* __restrict__ emaxe,
                          const float* __restrict__ e2, float* __restrict__ cst,
                          int* __restrict__ cnt) {
    int tid = threadIdx.x;  // 256
    // phase 0: per-token norms from z^2 partials
    float s = 0.f, m = 0.f;
    for (int i = tid; i < 16384; i += 256) {
        float t = zsumP[i] + zsumP[16384 + i] + zsumP[32768 + i] + zsumP[49152 + i];
        float nrm = sqrtf(t);
        s += nrm;
        m = fmaxf(m, nrm);
    }
    float zm = 0.f, el = 0.f, ee = 0.f;
    for (int i = tid; i < 1024; i += 256) zm = fmaxf(zm, zmax_part[i]);
    for (int i = tid; i < 2048; i += 256) { el = fmaxf(el, emaxl[i]); ee = fmaxf(ee, emaxe[i]); }
    __shared__ float S[256], M[256], Z[256], L[256], E[256];
    __shared__ float shv[3];   // inv_s, maxA, EPS2
    S[tid] = s; M[tid] = m; Z[tid] = zm; L[tid] = el; E[tid] = ee;
    __syncthreads();
    for (int off = 128; off > 0; off >>= 1) {
        if (tid < off) {
            S[tid] += S[tid + off];
            M[tid] = fmaxf(M[tid], M[tid + off]);
            Z[tid] = fmaxf(Z[tid], Z[tid + off]);
            L[tid] = fmaxf(L[tid], L[tid + off]);
            E[tid] = fmaxf(E[tid], E[tid + off]);
        }
        __syncthreads();
    }
    if (tid == 0) {
        float pre_len = S[0] * (1.0f / 16384.0f);
        float scale = (pre_len >= FIXLEN) ? (FIXLEN / pre_len) : 1.0f;
        cst[0] = scale;
        cst[1] = 1.0f / scale;
        cst[3] = M[0];
        float maxA  = M[0] * (1.0f / 30.0f);
        float maxEl = sqrtf(L[0]);
        float maxE  = sqrtf(E[0]);
        float maxZl = 2.0f * sqrtf(Z[0]);
        float eps = 2.0f * (maxA * maxEl + maxZl * maxE + maxZl * maxEl) + 0.03f;
        cst[2] = 2.0f * eps;
        cnt[0] = 0;
        cnt[1] = 0;
        shv[0] = 1.0f / scale;
        shv[1] = maxA;
        shv[2] = 2.0f * eps;
    }
    __syncthreads();
    float inv_s = shv[0], maxA = shv[1];
    // phase 2: T = min_n UB(n), UB = e2*inv_s + 2*maxA*sqrt(e2)
    float tmin = 3.4e38f;
    for (int i = tid; i < 16384; i += 256) {
        float v = e2[i];
        float ub = fmaf(2.0f * maxA, sqrtf(v), v * inv_s);
        tmin = fminf(tmin, ub);
    }
    S[tid] = tmin;
    __syncthreads();
    for (int off = 128; off > 0; off >>= 1) {
        if (tid < off) S[tid] = fminf(S[tid], S[tid + off]);
        __syncthreads();
    }
    if (tid == 0) cst[4] = S[0] + 2.0f * shv[2] + 1.0f;   // T_cut: margin for fp32 eval error
}

// ---------------- K4: candidate selection: LB(n) <= T_cut ----------------
__global__ void k_select(const float* __restrict__ e2, const float* __restrict__ cst,
                         int* __restrict__ candIdx, int* __restrict__ cnt) {
    int n = blockIdx.x * 256 + threadIdx.x;   // grid 64
    float inv_s = cst[1], maxA = cst[3] * (1.0f / 30.0f), Tc = cst[4];
    float v = e2[n];
    float lb = fmaf(-2.0f * maxA, sqrtf(v), v * inv_s);
    bool sel = lb <= Tc;
    u64 mask = __ballot(sel);
    if (mask) {
        int lane = threadIdx.x & 63;
        int leader = __ffsll((long long)mask) - 1;
        int base = 0;
        if (lane == leader) base = atomicAdd(cnt + 1, __popcll(mask));
        base = __shfl(base, leader);
        if (sel) {
            int rank = __popcll(mask & ((1ull << lane) - 1ull));
            candIdx[base + rank] = n;
        }
    }
}

// ---------------- K5: gather candidate rows -> fp16 plane + scaled e2 (padded) ----------------
__global__ void k_gather(const float* __restrict__ emb, const float* __restrict__ e2,
                         const float* __restrict__ cst, const int* __restrict__ cnt,
                         const int* __restrict__ candIdx, u16* __restrict__ ehc,
                         float* __restrict__ ce2) {
    int w = threadIdx.x >> 6, lane = threadIdx.x & 63;
    int wid = blockIdx.x * 4 + w;   // grid 64 -> 256 waves
    int C = cnt[1];
    int NP = (C + 127) & ~127;
    float inv_s = cst[1];
    for (int slot = wid; slot < NP; slot += 256) {
        if (slot < C) {
            int n = candIdx[slot];
            float4 v = *(const float4*)&emb[(size_t)n * 256 + lane * 4];
            u32 p0 = (u32)__half_as_ushort(__float2half(v.x)) |
                     ((u32)__half_as_ushort(__float2half(v.y)) << 16);
            u32 p1 = (u32)__half_as_ushort(__float2half(v.z)) |
                     ((u32)__half_as_ushort(__float2half(v.w)) << 16);
            *(uint2*)&ehc[(size_t)slot * 256 + lane * 4] = make_uint2(p0, p1);
            if (lane == 0) ce2[slot] = e2[n] * inv_s;
        } else {
            *(uint2*)&ehc[(size_t)slot * 256 + lane * 4] = make_uint2(0u, 0u);
            if (lane == 0) ce2[slot] = 3.0e37f;   // pad: never wins
        }
    }
}

// ---------------- K6: candidate fp16 MFMA GEMM (round-2 verified structure, dynamic chunks) ---
// 256 threads = 4 waves (2M x 2N), block = 128 tokens x all candidates (chunks of 128).
// LDS 80 KB: A plane 64 KB resident + B dbuf 2 x 8 KB.  Packed keys: 9-bit code (chunk*4+tj),
// perturbation <= 2^9 ulp(256) ~ 0.016 < the 0.03 additive EPS2 margin.  pv1 stores SLOT.
__launch_bounds__(256, 2)
__global__ void k_cmfma(const u16* __restrict__ zh, const u16* __restrict__ ehc,
                        const float* __restrict__ ce2, const int* __restrict__ cnt,
                        u64* __restrict__ pv1, float* __restrict__ pvb2) {
    __shared__ __align__(16) char lds[81920];
    char* sAb = lds;                    // 64 KB: [128 rows][32 slots16], slot^=(row&7) low3
    char* sB0 = lds + 65536;            // 8 KB:  [128 rows][4 slots16], slot^=((row>>1)&3)
    char* sB1 = lds + 73728;            // 8 KB

    int tokT = blockIdx.x;              // grid = 128
    int t0 = tokT * 128;
    int nch = (cnt[1] + 127) >> 7;      // dynamic candidate chunks
    int tid = threadIdx.x, w = tid >> 6, lane = tid & 63;
    int ml = lane & 15, q = lane >> 4;
    int wm0 = (w & 1) * 64, wn0 = (w >> 1) * 64;
    int x7 = ml & 7;
    int xb = (ml >> 1) & 3;

    // prologue: stage A plane (16 granules/thread), source-XOR swizzle
    #pragma unroll
    for (int i = 0; i < 16; ++i) {
        int el = i * 256 + tid;
        int row = el >> 5, j = el & 31;
        int jsrc = (j & 24) | ((j & 7) ^ (row & 7));
        gl_lds16(zh + (size_t)(t0 + row) * 256 + jsrc * 8, sAb + el * 16);
    }
    // prologue: stage B chunk0 slice0 -> sB0
    #pragma unroll
    for (int i = 0; i < 2; ++i) {
        int el = i * 256 + tid;
        int row = el >> 2, j = el & 3;
        int jsrc = j ^ ((row >> 1) & 3);
        gl_lds16(ehc + (size_t)row * 256 + jsrc * 8, sB0 + el * 16);
    }

    float etb[4], etn[4];
    #pragma unroll
    for (int tj = 0; tj < 4; ++tj) etb[tj] = ce2[wn0 + tj * 16 + ml];

    float b1[16], b2[16];
    #pragma unroll
    for (int k = 0; k < 16; ++k) { b1[k] = 3.4e38f; b2[k] = 3.4e38f; }

    int ncol0 = wn0 + ml;

    #pragma unroll 1
    for (int c = 0; c < nch; ++c) {
        int nc = c * 128;
        f32x4 acc[4][4];
        #pragma unroll
        for (int ti = 0; ti < 4; ++ti)
            #pragma unroll
            for (int tj = 0; tj < 4; ++tj)
                acc[ti][tj] = (f32x4){etb[tj], etb[tj], etb[tj], etb[tj]};
        if (c + 1 < nch) {
            #pragma unroll
            for (int tj = 0; tj < 4; ++tj)
                etn[tj] = ce2[nc + 128 + wn0 + tj * 16 + ml];
        }
        #pragma unroll
        for (int s = 0; s < 8; ++s) {
            __syncthreads();   // drains stage issued last slice (implicit vmcnt(0))
            if (s < 7 || c + 1 < nch) {
                int s2 = (s + 1) & 7;
                int cc2 = (s == 7) ? (c + 1) : c;
                char* dst = (s & 1) ? sB0 : sB1;
                #pragma unroll
                for (int i = 0; i < 2; ++i) {
                    int el = i * 256 + tid;
                    int row = el >> 2, j = el & 3;
                    int jsrc = j ^ ((row >> 1) & 3);
                    gl_lds16(ehc + (size_t)(cc2 * 128 + row) * 256 + s2 * 32 + jsrc * 8,
                             dst + el * 16);
                }
            }
            __builtin_amdgcn_sched_barrier(0);
            const char* sB = (s & 1) ? sB1 : sB0;
            half8 A[4], B[4];
            int slB = q ^ xb;
            #pragma unroll
            for (int tj = 0; tj < 4; ++tj)
                B[tj] = *(const half8*)(sB + (wn0 + tj * 16 + ml) * 64 + slB * 16);
            int slotA = (s >> 1) * 8 + ((((s & 1) * 4) + q) ^ x7);
            #pragma unroll
            for (int ti = 0; ti < 4; ++ti)
                A[ti] = *(const half8*)(sAb + (wm0 + ti * 16 + ml) * 512 + slotA * 16);
            #pragma unroll
            for (int ti = 0; ti < 4; ++ti)
                #pragma unroll
                for (int tj = 0; tj < 4; ++tj)
                    acc[ti][tj] = __builtin_amdgcn_mfma_f32_16x16x32_f16(A[ti], B[tj], acc[ti][tj], 0, 0, 0);
        }
        // packed-key top-2 update: 9-bit code in mantissa low bits
        u32 code0 = (u32)(c * 4);
        #pragma unroll
        for (int ti = 0; ti < 4; ++ti) {
            #pragma unroll
            for (int r = 0; r < 4; ++r) {
                int k = ti * 4 + r;
                #pragma unroll
                for (int tj = 0; tj < 4; ++tj) {
                    u32 kb = (__float_as_uint(acc[ti][tj][r]) & 0xFFFFFE00u) | (code0 + (u32)tj);
                    float key = __uint_as_float(kb);
                    b2[k] = __builtin_amdgcn_fmed3f(key, b1[k], b2[k]);
                    b1[k] = fminf(b1[k], key);
                }
            }
        }
        if (c + 1 < nch) {
            #pragma unroll
            for (int tj = 0; tj < 4; ++tj) etb[tj] = etn[tj];
        }
    }

    // decode packed slot indices
    int i1[16];
    #pragma unroll
    for (int k = 0; k < 16; ++k) {
        u32 code = __float_as_uint(b1[k]) & 511u;
        i1[k] = ncol0 + (int)((code >> 2) << 7) + (int)((code & 3) << 4);
    }

    // cross-lane merge over ml (masks 1,2,4,8); ties fall to refine via b2
    #pragma unroll
    for (int k = 0; k < 16; ++k) {
        #pragma unroll
        for (int m = 1; m < 16; m <<= 1) {
            float o1 = __shfl_xor(b1[k], m);
            int   oi = __shfl_xor(i1[k], m);
            float o2 = __shfl_xor(b2[k], m);
            float big = fmaxf(b1[k], o1);
            b2[k] = fminf(fminf(b2[k], o2), big);
            bool cnd = o1 < b1[k];
            i1[k] = cnd ? oi : i1[k];
            b1[k] = fminf(b1[k], o1);
        }
    }
    __syncthreads();   // all LDS compute reads done; overlay merge arrays on B region
    float* m1s = (float*)sB0;            // [128]
    int*   mis = (int*)(sB0 + 512);      // [128]
    float* m2s = (float*)(sB0 + 1024);   // [128]
    if (w < 2 && ml == 0) {
        #pragma unroll
        for (int ti = 0; ti < 4; ++ti)
            #pragma unroll
            for (int r = 0; r < 4; ++r) {
                int mr = wm0 + ti * 16 + q * 4 + r;
                int k = ti * 4 + r;
                m1s[mr] = b1[k]; mis[mr] = i1[k]; m2s[mr] = b2[k];
            }
    }
    __syncthreads();
    if (w >= 2 && ml == 0) {
        #pragma unroll
        for (int ti = 0; ti < 4; ++ti)
            #pragma unroll
            for (int r = 0; r < 4; ++r) {
                int mr = wm0 + ti * 16 + q * 4 + r;
                int k = ti * 4 + r;
                float a1 = m1s[mr]; int ai = mis[mr]; float a2 = m2s[mr];
                float f1, f2; int fi;
                if (a1 < b1[k]) { f1 = a1; fi = ai; f2 = fminf(a2, b1[k]); }
                else            { f1 = b1[k]; fi = i1[k]; f2 = fminf(b2[k], a1); }
                int t = t0 + mr;
                pv1[t] = ((u64)fkey(f1) << 32) | (u32)fi;   // fi = candidate SLOT
                pvb2[t] = f2;
            }
    }
}

// ---------------- K7: certify per token (sec clamped by T_cut); build uncertified list -------
__global__ void k_refine(const u64* __restrict__ pv1, const float* __restrict__ pvb2,
                         const float* __restrict__ cst, const int* __restrict__ candIdx,
                         int* __restrict__ bestn, int* __restrict__ list, int* __restrict__ cnt) {
    int t = blockIdx.x * 256 + threadIdx.x;   // grid 64
    float EPS2 = cst[2], Tc = cst[4];
    u64 u = pv1[t];
    float d1 = fdec((u32)(u >> 32));
    int slot = (int)(u32)(u & 0xFFFFFFFFull);
    float sec = fminf(pvb2[t], Tc);   // non-candidates provably have d > Tc
    bool cert = sec > d1 + EPS2;
    if (cert) bestn[t] = candIdx[slot];
    u64 mask = __ballot(!cert);
    if (mask) {
        int lane = threadIdx.x & 63;
        int leader = __ffsll((long long)mask) - 1;
        int base = 0;
        if (lane == leader) base = atomicAdd(cnt, __popcll(mask));
        base = __shfl(base, leader);
        if (!cert) {
            int rank = __popcll(mask & ((1ull << lane) - 1ull));
            list[base + rank] = t;
        }
    }
}

// ---------------- K8: exact refinement over the candidate list, one wave per token ------------
__global__ void k_refine2(const float* __restrict__ z, const float* __restrict__ emb,
                          const float* __restrict__ e2, const float* __restrict__ cst,
                          const int* __restrict__ cnt, const int* __restrict__ list,
                          const int* __restrict__ candIdx, int* __restrict__ bestn) {
    __shared__ float az[4][256];
    int w = threadIdx.x >> 6, lane = threadIdx.x & 63;
    int wid = blockIdx.x * 4 + w;              // grid 64 -> 256 waves
    int NR = cnt[0], C = cnt[1];
    float inv_s = cst[1];
    for (int it = wid; it < NR; it += 256) {
        int t = list[it];
        int b = t >> 10, hw = t & 1023;
        #pragma unroll
        for (int j = 0; j < 4; ++j)
            az[w][lane + 64 * j] = z[(size_t)b * 262144 + (size_t)(lane + 64 * j) * 1024 + hw] * (1.0f / 30.0f);
        float4 a4 = *(const float4*)&az[w][lane * 4];
        float bestv = 3.4e38f; int bi = 0x7fffffff;
        for (int slot = 0; slot < C; ++slot) {
            int n = candIdx[slot];
            float4 e4 = *(const float4*)&emb[(size_t)n * 256 + lane * 4];
            float s = a4.x * e4.x + a4.y * e4.y + a4.z * e4.z + a4.w * e4.w;
            #pragma unroll
            for (int m = 1; m < 64; m <<= 1) s += __shfl_xor(s, m);
            float d = fmaf(-2.0f, s, e2[n] * inv_s);
            if (d < bestv || (d == bestv && n < bi)) { bestv = d; bi = n; }
        }
        if (lane == 0) bestn[t] = bi;
    }
}

// ---------------- K9: emit z_q, idx, diff partials ----------------
__global__ void k_emit(const float* __restrict__ z, const float* __restrict__ emb,
                       const float* __restrict__ cst, const int* __restrict__ bestn,
                       float* __restrict__ out, float* __restrict__ diff_part) {
    int blk = blockIdx.x;                 // 256
    int cq = blk >> 6, sub = blk & 63;
    int b = sub >> 2;
    int tl = (sub & 3) * 256 + threadIdx.x;
    int t = b * 1024 + tl;
    int bi = bestn[t];
    if (cq == 0) out[4194305 + t] = (float)bi;
    float scale = cst[0];
    const float* er = emb + (size_t)bi * 256 + cq * 64;
    const float* zr = z + (size_t)b * 262144 + (size_t)cq * 65536 + tl;
    float* orow = out + (size_t)b * 262144 + (size_t)cq * 65536 + tl;
    float ds = 0.f;
    #pragma unroll 8
    for (int j = 0; j < 64; ++j) {
        float qv = er[j] * FIXLEN;
        float zt = zr[(size_t)j << 10] * scale;
        float dd = qv - zt;
        ds = fmaf(dd, dd, ds);
        orow[(size_t)j << 10] = qv;
    }
    __shared__ float red[256];
    red[threadIdx.x] = ds;
    __syncthreads();
    for (int off = 128; off > 0; off >>= 1) {
        if (threadIdx.x < off) red[threadIdx.x] += red[threadIdx.x + off];
        __syncthreads();
    }
    if (threadIdx.x == 0) diff_part[blk] = red[0];
}

// ---------------- K10: finalize diff ----------------
__global__ void k_diff(const float* __restrict__ diff_part, float* __restrict__ out) {
    int tid = threadIdx.x;   // 256
    __shared__ float red[256];
    red[tid] = diff_part[tid];
    __syncthreads();
    for (int off = 128; off > 0; off >>= 1) {
        if (tid < off) red[tid] += red[tid + off];
        __syncthreads();
    }
    if (tid == 0) out[4194304] = BETA * red[0] / 4194304.0f;
}

extern "C" void kernel_launch(void* const* d_in, const int* in_sizes, int n_in,
                              void* d_out, int out_size, void* d_ws, size_t ws_size,
                              hipStream_t stream) {
    const float* z   = (const float*)d_in[0];
    const float* emb = (const float*)d_in[1];
    float* out = (float*)d_out;
    char* wsb = (char*)d_ws;

    float* cst       = (float*)(wsb + CST_OFF);
    int*   cnt       = (int*)(wsb + CNT_OFF);
    float* diff_part = (float*)(wsb + DIFF_OFF);
    float* zmax_part = (float*)(wsb + ZMAX_OFF);
    float* emaxl     = (float*)(wsb + EMAXL_OFF);
    float* emaxe     = (float*)(wsb + EMAXE_OFF);
    float* e2        = (float*)(wsb + E2_OFF);
    int*   bestn     = (int*)(wsb + BESTN_OFF);
    int*   list      = (int*)(wsb + LIST_OFF);
    u64*   pv1       = (u64*)(wsb + PV1_OFF);
    int*   candIdx   = (int*)(wsb + CIDX_OFF);
    float* ce2       = (float*)(wsb + CE2_OFF);
    float* pvb2      = (float*)(wsb + PVB2_OFF);
    float* zsumP     = (float*)(wsb + ZS_OFF);
    u16*   zh        = (u16*)(wsb + ZH_OFF);
    u16*   ehc       = (u16*)(wsb + EHC_OFF);

    k_split_e<<<2048, 256, 0, stream>>>(emb, e2, emaxl, emaxe);
    k_split_z<<<1024, 256, 0, stream>>>(z, zh, zmax_part, zsumP);
    k_scalars<<<1, 256, 0, stream>>>(zsumP, zmax_part, emaxl, emaxe, e2, cst, cnt);
    k_select<<<64, 256, 0, stream>>>(e2, cst, candIdx, cnt);
    k_gather<<<64, 256, 0, stream>>>(emb, e2, cst, cnt, candIdx, ehc, ce2);
    k_cmfma<<<128, 256, 0, stream>>>(zh, ehc, ce2, cnt, pv1, pvb2);
    k_refine<<<64, 256, 0, stream>>>(pv1, pvb2, cst, candIdx, bestn, list, cnt);
    k_refine2<<<64, 256, 0, stream>>>(z, emb, e2, cst, cnt, list, candIdx, bestn);
    k_emit<<<256, 256, 0, stream>>>(z, emb, cst, bestn, out, diff_part);
    k_diff<<<1, 256, 0, stream>>>(diff_part, out);
}

// Round 7
// 206.758 us; speedup vs baseline: 2.1768x; 2.1768x over previous
//
#include <hip/hip_runtime.h>
#include <hip/hip_fp16.h>
#include <math.h>

#define FIXLEN 30.0f
#define BETA   0.25f

typedef unsigned short u16;
typedef unsigned int   u32;
typedef unsigned long long u64;
typedef _Float16 half8 __attribute__((ext_vector_type(8)));
typedef float    f32x4 __attribute__((ext_vector_type(4)));

// ---------------- ws layout (bytes) ----------------
#define CST_OFF    512       // f[16]: 0=scale,1=inv_s,2=EPS2,3=maxNrm,4=T_cut
#define CNT_OFF    576       // i[2]: 1=cand cnt
#define DIFF_OFF   1024      // f[256]
#define ZMAX_OFF   2048      // f[1024]
#define EMAXL_OFF  6144      // f[2048]
#define EMAXE_OFF  14336     // f[2048]
#define E2_OFF     22528     // f[16384] -> 88064
#define BESTN_OFF  88064     // i[16384] -> 153600
#define PCNT_OFF   153600    // i[16384] per-token pair count -> 219136
#define PLIST_OFF  219136    // i[16384*8] per-token candidate slots -> 743424
#define CIDX_OFF   743424    // i[16384] -> 808960
#define CE2_OFF    808960    // f[16384] -> 874496
#define ZS_OFF     1048576   // f[4*16384] z^2 partials -> 1310720
#define ZH_OFF     1792000   // half[16384*256] -> 10180608
#define EHC_OFF    10180608  // half[16384*256] gathered candidate plane -> 18569216

__device__ inline void gl_lds16(const void* g, void* l) {
    __builtin_amdgcn_global_load_lds(
        (const __attribute__((address_space(1))) unsigned int*)g,
        (__attribute__((address_space(3))) unsigned int*)l, 16, 0, 0);
}

// ---------------- K1: emb -> e2 + residual-norm maxes ----------------
__global__ void k_split_e(const float* __restrict__ emb, float* __restrict__ e2,
                          float* __restrict__ emaxl, float* __restrict__ emaxe) {
    int gidx = blockIdx.x * 256 + threadIdx.x;   // grid = 2048
    int n = gidx >> 5;
    int c8 = (gidx & 31) * 8;
    const float* ep = emb + (size_t)n * 256 + c8;
    float4 v0 = *(const float4*)ep;
    float4 v1 = *(const float4*)(ep + 4);
    float vv[8] = {v0.x, v0.y, v0.z, v0.w, v1.x, v1.y, v1.z, v1.w};
    float s2 = 0.f, r2 = 0.f;
    #pragma unroll
    for (int k = 0; k < 8; ++k) {
        __half h = __float2half(vv[k]);
        float r = vv[k] - __half2float(h);
        s2 = fmaf(vv[k], vv[k], s2);
        r2 = fmaf(r, r, r2);
    }
    #pragma unroll
    for (int off = 16; off > 0; off >>= 1) {
        s2 += __shfl_down(s2, off, 32);
        r2 += __shfl_down(r2, off, 32);
    }
    __shared__ float L1[8], L2[8];
    if ((threadIdx.x & 31) == 0) {
        e2[n] = s2;
        L1[threadIdx.x >> 5] = r2;
        L2[threadIdx.x >> 5] = s2;
    }
    __syncthreads();
    if (threadIdx.x == 0) {
        float a = 0.f, bmax = 0.f;
        #pragma unroll
        for (int i = 0; i < 8; ++i) { a = fmaxf(a, L1[i]); bmax = fmaxf(bmax, L2[i]); }
        emaxl[blockIdx.x] = a;
        emaxe[blockIdx.x] = bmax;
    }
}

// ---------------- K2: z -> fp16(-2*z/30) plane (transpose) + residual max + z^2 partials ------
__global__ void k_split_z(const float* __restrict__ z, u16* __restrict__ zh,
                          float* __restrict__ zmax_part, float* __restrict__ zsumP) {
    int bi = blockIdx.x;                     // grid = 1024
    int b = bi >> 6, rest = bi & 63;
    int c0 = (rest >> 4) * 64, s0 = (rest & 15) * 64;
    __shared__ float ld[64][65];
    __shared__ float red2[64][4];
    __shared__ float redz[64][4];
    __shared__ float rmax[64];
    int tid = threadIdx.x;
    #pragma unroll
    for (int p = 0; p < 16; ++p) {
        int idx = p * 256 + tid;
        int cc = idx >> 6, ss = idx & 63;
        ld[cc][ss] = z[(size_t)b * 262144 + (size_t)(c0 + cc) * 1024 + s0 + ss];
    }
    __syncthreads();
    int ss2 = tid >> 2, cq = tid & 3;
    int t = b * 1024 + s0 + ss2;
    float r2 = 0.f, zacc = 0.f;
    u32 pk[8];
    #pragma unroll
    for (int k = 0; k < 8; ++k) pk[k] = 0;
    #pragma unroll
    for (int j = 0; j < 16; ++j) {
        float raw = ld[cq * 16 + j][ss2];
        zacc = fmaf(raw, raw, zacc);
        float v = raw * (1.0f / 30.0f);
        __half h = __float2half(v);
        float vh = __half2float(h);
        float r = v - vh;
        r2 = fmaf(r, r, r2);
        __half hs = __float2half(-2.0f * vh);   // exact power-of-2 scale
        pk[j >> 1] |= ((u32)__half_as_ushort(hs)) << ((j & 1) * 16);
    }
    u16* dst = zh + (size_t)t * 256 + c0 + cq * 16;
    *(uint4*)dst = make_uint4(pk[0], pk[1], pk[2], pk[3]);
    *(uint4*)(dst + 8) = make_uint4(pk[4], pk[5], pk[6], pk[7]);
    red2[ss2][cq] = r2;
    redz[ss2][cq] = zacc;
    __syncthreads();
    if (tid < 64) {
        rmax[tid] = red2[tid][0] + red2[tid][1] + red2[tid][2] + red2[tid][3];
        zsumP[(size_t)(rest >> 4) * 16384 + b * 1024 + s0 + tid] =
            redz[tid][0] + redz[tid][1] + redz[tid][2] + redz[tid][3];
    }
    __syncthreads();
    for (int off = 32; off > 0; off >>= 1) {
        if (tid < off) rmax[tid] = fmaxf(rmax[tid], rmax[tid + off]);
        __syncthreads();
    }
    if (tid == 0) zmax_part[bi] = rmax[0];
}

// ---------------- K3: scalars: scale + EPS2 + T_cut ----------------
__global__ void k_scalars(const float* __restrict__ zsumP, const float* __restrict__ zmax_part,
                          const float* __restrict__ emaxl, const float* __restrict__ emaxe,
                          const float* __restrict__ e2, float* __restrict__ cst,
                          int* __restrict__ cnt) {
    int tid = threadIdx.x;  // 256
    float s = 0.f, m = 0.f;
    for (int i = tid; i < 16384; i += 256) {
        float t = zsumP[i] + zsumP[16384 + i] + zsumP[32768 + i] + zsumP[49152 + i];
        float nrm = sqrtf(t);
        s += nrm;
        m = fmaxf(m, nrm);
    }
    float zm = 0.f, el = 0.f, ee = 0.f;
    for (int i = tid; i < 1024; i += 256) zm = fmaxf(zm, zmax_part[i]);
    for (int i = tid; i < 2048; i += 256) { el = fmaxf(el, emaxl[i]); ee = fmaxf(ee, emaxe[i]); }
    __shared__ float S[256], M[256], Z[256], L[256], E[256];
    __shared__ float shv[3];   // inv_s, maxA, EPS2
    S[tid] = s; M[tid] = m; Z[tid] = zm; L[tid] = el; E[tid] = ee;
    __syncthreads();
    for (int off = 128; off > 0; off >>= 1) {
        if (tid < off) {
            S[tid] += S[tid + off];
            M[tid] = fmaxf(M[tid], M[tid + off]);
            Z[tid] = fmaxf(Z[tid], Z[tid + off]);
            L[tid] = fmaxf(L[tid], L[tid + off]);
            E[tid] = fmaxf(E[tid], E[tid + off]);
        }
        __syncthreads();
    }
    if (tid == 0) {
        float pre_len = S[0] * (1.0f / 16384.0f);
        float scale = (pre_len >= FIXLEN) ? (FIXLEN / pre_len) : 1.0f;
        cst[0] = scale;
        cst[1] = 1.0f / scale;
        cst[3] = M[0];
        float maxA  = M[0] * (1.0f / 30.0f);
        float maxEl = sqrtf(L[0]);
        float maxE  = sqrtf(E[0]);
        float maxZl = 2.0f * sqrtf(Z[0]);
        float eps = 2.0f * (maxA * maxEl + maxZl * maxE + maxZl * maxEl) + 0.03f;
        cst[2] = 2.0f * eps;
        cnt[0] = 0;
        cnt[1] = 0;
        shv[0] = 1.0f / scale;
        shv[1] = maxA;
        shv[2] = 2.0f * eps;
    }
    __syncthreads();
    float inv_s = shv[0], maxA = shv[1];
    float tmin = 3.4e38f;
    for (int i = tid; i < 16384; i += 256) {
        float v = e2[i];
        float ub = fmaf(2.0f * maxA, sqrtf(v), v * inv_s);
        tmin = fminf(tmin, ub);
    }
    S[tid] = tmin;
    __syncthreads();
    for (int off = 128; off > 0; off >>= 1) {
        if (tid < off) S[tid] = fminf(S[tid], S[tid + off]);
        __syncthreads();
    }
    if (tid == 0) cst[4] = S[0] + 2.0f * shv[2] + 1.0f;   // T_cut
}

// ---------------- K4: candidate selection (+ pcnt zero) ----------------
__global__ void k_select(const float* __restrict__ e2, const float* __restrict__ cst,
                         int* __restrict__ candIdx, int* __restrict__ cnt,
                         int* __restrict__ pcnt) {
    int n = blockIdx.x * 256 + threadIdx.x;   // grid 64
    pcnt[n] = 0;
    float inv_s = cst[1], maxA = cst[3] * (1.0f / 30.0f), Tc = cst[4];
    float v = e2[n];
    float lb = fmaf(-2.0f * maxA, sqrtf(v), v * inv_s);
    bool sel = lb <= Tc;
    u64 mask = __ballot(sel);
    if (mask) {
        int lane = threadIdx.x & 63;
        int leader = __ffsll((long long)mask) - 1;
        int base = 0;
        if (lane == leader) base = atomicAdd(cnt + 1, __popcll(mask));
        base = __shfl(base, leader);
        if (sel) {
            int rank = __popcll(mask & ((1ull << lane) - 1ull));
            candIdx[base + rank] = n;
        }
    }
}

// ---------------- K5: gather candidate rows -> fp16 plane + scaled e2 (padded) ----------------
__global__ void k_gather(const float* __restrict__ emb, const float* __restrict__ e2,
                         const float* __restrict__ cst, const int* __restrict__ cnt,
                         const int* __restrict__ candIdx, u16* __restrict__ ehc,
                         float* __restrict__ ce2) {
    int w = threadIdx.x >> 6, lane = threadIdx.x & 63;
    int wid = blockIdx.x * 4 + w;   // grid 64 -> 256 waves
    int C = cnt[1];
    int NP = (C + 127) & ~127;
    float inv_s = cst[1];
    for (int slot = wid; slot < NP; slot += 256) {
        if (slot < C) {
            int n = candIdx[slot];
            float4 v = *(const float4*)&emb[(size_t)n * 256 + lane * 4];
            u32 p0 = (u32)__half_as_ushort(__float2half(v.x)) |
                     ((u32)__half_as_ushort(__float2half(v.y)) << 16);
            u32 p1 = (u32)__half_as_ushort(__float2half(v.z)) |
                     ((u32)__half_as_ushort(__float2half(v.w)) << 16);
            *(uint2*)&ehc[(size_t)slot * 256 + lane * 4] = make_uint2(p0, p1);
            if (lane == 0) ce2[slot] = e2[n] * inv_s;
        } else {
            *(uint2*)&ehc[(size_t)slot * 256 + lane * 4] = make_uint2(0u, 0u);
            if (lane == 0) ce2[slot] = 3.0e37f;   // pad: never near the min
        }
    }
}

// ---------------- K6: candidate GEMM, two-pass: (1) per-token min d1, (2) emit near-tie pairs -
// 256 threads = 4 waves (2M x 2N), block = 128 tokens x all candidates (chunks of 128).
// Pass 2 recomputes the identical (bitwise-deterministic) MFMA stream and emits every
// (token, slot) with d_fp16 <= d1 + EPS2 + eps into per-token lists (cap 8; overflow ->
// k_exact full-scan fallback).  The emitted set provably contains the true argmin.
__launch_bounds__(256, 2)
__global__ void k_cmfma(const u16* __restrict__ zh, const u16* __restrict__ ehc,
                        const float* __restrict__ ce2, const float* __restrict__ cst,
                        const int* __restrict__ cnt, int* __restrict__ pcnt,
                        int* __restrict__ plist) {
    __shared__ __align__(16) char lds[81920];
    char* sAb = lds;                    // 64 KB: [128 rows][32 slots16], slot^=(row&7) low3
    char* sB0 = lds + 65536;            // 8 KB
    char* sB1 = lds + 73728;            // 8 KB

    int t0 = blockIdx.x * 128;          // grid = 128
    int nch = (cnt[1] + 127) >> 7;
    float THR = cst[2] + 0.0625f;       // EPS2 + slack (extra emission is always sound)
    int tid = threadIdx.x, w = tid >> 6, lane = tid & 63;
    int ml = lane & 15, q = lane >> 4;
    int wm0 = (w & 1) * 64, wn0 = (w >> 1) * 64;
    int x7 = ml & 7;
    int xb = (ml >> 1) & 3;
    int slB = q ^ xb;

    // prologue: stage A plane (resident for both passes)
    #pragma unroll
    for (int i = 0; i < 16; ++i) {
        int el = i * 256 + tid;
        int row = el >> 5, j = el & 31;
        int jsrc = (j & 24) | ((j & 7) ^ (row & 7));
        gl_lds16(zh + (size_t)(t0 + row) * 256 + jsrc * 8, sAb + el * 16);
    }
    // prologue: stage B chunk0 slice0 -> sB0
    #pragma unroll
    for (int i = 0; i < 2; ++i) {
        int el = i * 256 + tid;
        int row = el >> 2, j = el & 3;
        int jsrc = j ^ ((row >> 1) & 3);
        gl_lds16(ehc + (size_t)row * 256 + jsrc * 8, sB0 + el * 16);
    }

    float b1[16];
    #pragma unroll
    for (int k = 0; k < 16; ++k) b1[k] = 3.4e38f;

    // ---------------- pass 1: per-row min ----------------
    #pragma unroll 1
    for (int c = 0; c < nch; ++c) {
        float etb[4];
        #pragma unroll
        for (int tj = 0; tj < 4; ++tj) etb[tj] = ce2[c * 128 + wn0 + tj * 16 + ml];
        f32x4 acc[4][4];
        #pragma unroll
        for (int ti = 0; ti < 4; ++ti)
            #pragma unroll
            for (int tj = 0; tj < 4; ++tj)
                acc[ti][tj] = (f32x4){etb[tj], etb[tj], etb[tj], etb[tj]};
        #pragma unroll
        for (int s = 0; s < 8; ++s) {
            __syncthreads();
            if (s < 7 || c + 1 < nch) {
                int s2 = (s + 1) & 7;
                int cc2 = (s == 7) ? (c + 1) : c;
                char* dst = (s & 1) ? sB0 : sB1;
                #pragma unroll
                for (int i = 0; i < 2; ++i) {
                    int el = i * 256 + tid;
                    int row = el >> 2, j = el & 3;
                    int jsrc = j ^ ((row >> 1) & 3);
                    gl_lds16(ehc + (size_t)(cc2 * 128 + row) * 256 + s2 * 32 + jsrc * 8,
                             dst + el * 16);
                }
            }
            __builtin_amdgcn_sched_barrier(0);
            const char* sB = (s & 1) ? sB1 : sB0;
            half8 A[4], B[4];
            #pragma unroll
            for (int tj = 0; tj < 4; ++tj)
                B[tj] = *(const half8*)(sB + (wn0 + tj * 16 + ml) * 64 + slB * 16);
            int slotA = (s >> 1) * 8 + ((((s & 1) * 4) + q) ^ x7);
            #pragma unroll
            for (int ti = 0; ti < 4; ++ti)
                A[ti] = *(const half8*)(sAb + (wm0 + ti * 16 + ml) * 512 + slotA * 16);
            #pragma unroll
            for (int ti = 0; ti < 4; ++ti)
                #pragma unroll
                for (int tj = 0; tj < 4; ++tj)
                    acc[ti][tj] = __builtin_amdgcn_mfma_f32_16x16x32_f16(A[ti], B[tj], acc[ti][tj], 0, 0, 0);
        }
        #pragma unroll
        for (int ti = 0; ti < 4; ++ti)
            #pragma unroll
            for (int r = 0; r < 4; ++r)
                #pragma unroll
                for (int tj = 0; tj < 4; ++tj)
                    b1[ti * 4 + r] = fminf(b1[ti * 4 + r], acc[ti][tj][r]);
    }

    // merge mins: cross-lane over ml, then cross-wave via LDS
    #pragma unroll
    for (int k = 0; k < 16; ++k) {
        #pragma unroll
        for (int m = 1; m < 16; m <<= 1)
            b1[k] = fminf(b1[k], __shfl_xor(b1[k], m));
    }
    __syncthreads();   // all pass-1 B reads done; overlay d1s on sB0
    float* d1s = (float*)sB0;   // [128]
    if (w < 2 && ml == 0) {
        #pragma unroll
        for (int ti = 0; ti < 4; ++ti)
            #pragma unroll
            for (int r = 0; r < 4; ++r)
                d1s[wm0 + ti * 16 + q * 4 + r] = b1[ti * 4 + r];
    }
    __syncthreads();
    if (w >= 2 && ml == 0) {
        #pragma unroll
        for (int ti = 0; ti < 4; ++ti)
            #pragma unroll
            for (int r = 0; r < 4; ++r) {
                int mr = wm0 + ti * 16 + q * 4 + r;
                d1s[mr] = fminf(d1s[mr], b1[ti * 4 + r]);
            }
    }
    __syncthreads();
    float limit[16];
    #pragma unroll
    for (int ti = 0; ti < 4; ++ti)
        #pragma unroll
        for (int r = 0; r < 4; ++r)
            limit[ti * 4 + r] = d1s[wm0 + ti * 16 + q * 4 + r] + THR;
    __syncthreads();   // done reading d1s; safe to restage over sB0

    // ---------------- pass 2: recompute + emit pairs ----------------
    #pragma unroll
    for (int i = 0; i < 2; ++i) {
        int el = i * 256 + tid;
        int row = el >> 2, j = el & 3;
        int jsrc = j ^ ((row >> 1) & 3);
        gl_lds16(ehc + (size_t)row * 256 + jsrc * 8, sB0 + el * 16);
    }
    #pragma unroll 1
    for (int c = 0; c < nch; ++c) {
        float etb[4];
        #pragma unroll
        for (int tj = 0; tj < 4; ++tj) etb[tj] = ce2[c * 128 + wn0 + tj * 16 + ml];
        f32x4 acc[4][4];
        #pragma unroll
        for (int ti = 0; ti < 4; ++ti)
            #pragma unroll
            for (int tj = 0; tj < 4; ++tj)
                acc[ti][tj] = (f32x4){etb[tj], etb[tj], etb[tj], etb[tj]};
        #pragma unroll
        for (int s = 0; s < 8; ++s) {
            __syncthreads();
            if (s < 7 || c + 1 < nch) {
                int s2 = (s + 1) & 7;
                int cc2 = (s == 7) ? (c + 1) : c;
                char* dst = (s & 1) ? sB0 : sB1;
                #pragma unroll
                for (int i = 0; i < 2; ++i) {
                    int el = i * 256 + tid;
                    int row = el >> 2, j = el & 3;
                    int jsrc = j ^ ((row >> 1) & 3);
                    gl_lds16(ehc + (size_t)(cc2 * 128 + row) * 256 + s2 * 32 + jsrc * 8,
                             dst + el * 16);
                }
            }
            __builtin_amdgcn_sched_barrier(0);
            const char* sB = (s & 1) ? sB1 : sB0;
            half8 A[4], B[4];
            #pragma unroll
            for (int tj = 0; tj < 4; ++tj)
                B[tj] = *(const half8*)(sB + (wn0 + tj * 16 + ml) * 64 + slB * 16);
            int slotA = (s >> 1) * 8 + ((((s & 1) * 4) + q) ^ x7);
            #pragma unroll
            for (int ti = 0; ti < 4; ++ti)
                A[ti] = *(const half8*)(sAb + (wm0 + ti * 16 + ml) * 512 + slotA * 16);
            #pragma unroll
            for (int ti = 0; ti < 4; ++ti)
                #pragma unroll
                for (int tj = 0; tj < 4; ++tj)
                    acc[ti][tj] = __builtin_amdgcn_mfma_f32_16x16x32_f16(A[ti], B[tj], acc[ti][tj], 0, 0, 0);
        }
        // emit near-tie pairs
        int slot0 = c * 128 + wn0 + ml;
        #pragma unroll
        for (int ti = 0; ti < 4; ++ti) {
            #pragma unroll
            for (int r = 0; r < 4; ++r) {
                int k = ti * 4 + r;
                int t = t0 + wm0 + ti * 16 + q * 4 + r;
                #pragma unroll
                for (int tj = 0; tj < 4; ++tj) {
                    if (acc[ti][tj][r] <= limit[k]) {
                        int pos = atomicAdd(&pcnt[t], 1);
                        if (pos < 8) plist[t * 8 + pos] = slot0 + tj * 16;
                    }
                }
            }
        }
    }
}

// ---------------- K7: exact fp32 eval of listed pairs, min per token ----------------
__global__ void k_exact(const float* __restrict__ z, const float* __restrict__ emb,
                        const float* __restrict__ e2, const float* __restrict__ cst,
                        const int* __restrict__ cnt, const int* __restrict__ pcnt,
                        const int* __restrict__ plist, const int* __restrict__ candIdx,
                        int* __restrict__ bestn) {
    __shared__ float az[64][260];
    int tid = threadIdx.x, w = tid >> 6, lane = tid & 63;
    int t0 = blockIdx.x * 64;            // grid = 256
    int b = t0 >> 10, hw0 = t0 & 1023;
    float inv_s = cst[1];
    int C = cnt[1];
    // coalesced z-column tile: az[token][c] = z/30
    #pragma unroll 4
    for (int p = 0; p < 64; ++p) {
        int idx = p * 256 + tid;
        int c = idx >> 6, tt = idx & 63;
        az[tt][c] = z[(size_t)b * 262144 + (size_t)c * 1024 + hw0 + tt] * (1.0f / 30.0f);
    }
    __syncthreads();
    for (int tt = w * 16; tt < w * 16 + 16; ++tt) {
        int t = t0 + tt;
        int pc = pcnt[t];
        if (pc == 1) {
            if (lane == 0) bestn[t] = candIdx[plist[t * 8]];
            continue;
        }
        float4 a4 = *(const float4*)&az[tt][lane * 4];
        float bestv = 3.4e38f; int bi = 0x7fffffff;
        if (pc <= 8) {
            for (int i = 0; i < pc; ++i) {
                int n = candIdx[plist[t * 8 + i]];
                float4 e4 = *(const float4*)&emb[(size_t)n * 256 + lane * 4];
                float s = a4.x * e4.x + a4.y * e4.y + a4.z * e4.z + a4.w * e4.w;
                #pragma unroll
                for (int m = 1; m < 64; m <<= 1) s += __shfl_xor(s, m);
                float d = fmaf(-2.0f, s, e2[n] * inv_s);
                if (d < bestv || (d == bestv && n < bi)) { bestv = d; bi = n; }
            }
        } else {
            // overflow fallback: exact scan over all candidates (rare)
            for (int slot = 0; slot < C; ++slot) {
                int n = candIdx[slot];
                float4 e4 = *(const float4*)&emb[(size_t)n * 256 + lane * 4];
                float s = a4.x * e4.x + a4.y * e4.y + a4.z * e4.z + a4.w * e4.w;
                #pragma unroll
                for (int m = 1; m < 64; m <<= 1) s += __shfl_xor(s, m);
                float d = fmaf(-2.0f, s, e2[n] * inv_s);
                if (d < bestv || (d == bestv && n < bi)) { bestv = d; bi = n; }
            }
        }
        if (lane == 0) bestn[t] = bi;
    }
}

// ---------------- K8: emit z_q, idx, diff partials ----------------
__global__ void k_emit(const float* __restrict__ z, const float* __restrict__ emb,
                       const float* __restrict__ cst, const int* __restrict__ bestn,
                       float* __restrict__ out, float* __restrict__ diff_part) {
    int blk = blockIdx.x;                 // 256
    int cq = blk >> 6, sub = blk & 63;
    int b = sub >> 2;
    int tl = (sub & 3) * 256 + threadIdx.x;
    int t = b * 1024 + tl;
    int bi = bestn[t];
    if (cq == 0) out[4194305 + t] = (float)bi;
    float scale = cst[0];
    const float* er = emb + (size_t)bi * 256 + cq * 64;
    const float* zr = z + (size_t)b * 262144 + (size_t)cq * 65536 + tl;
    float* orow = out + (size_t)b * 262144 + (size_t)cq * 65536 + tl;
    float ds = 0.f;
    #pragma unroll 8
    for (int j = 0; j < 64; ++j) {
        float qv = er[j] * FIXLEN;
        float zt = zr[(size_t)j << 10] * scale;
        float dd = qv - zt;
        ds = fmaf(dd, dd, ds);
        orow[(size_t)j << 10] = qv;
    }
    __shared__ float red[256];
    red[threadIdx.x] = ds;
    __syncthreads();
    for (int off = 128; off > 0; off >>= 1) {
        if (threadIdx.x < off) red[threadIdx.x] += red[threadIdx.x + off];
        __syncthreads();
    }
    if (threadIdx.x == 0) diff_part[blk] = red[0];
}

// ---------------- K9: finalize diff ----------------
__global__ void k_diff(const float* __restrict__ diff_part, float* __restrict__ out) {
    int tid = threadIdx.x;   // 256
    __shared__ float red[256];
    red[tid] = diff_part[tid];
    __syncthreads();
    for (int off = 128; off > 0; off >>= 1) {
        if (tid < off) red[tid] += red[tid + off];
        __syncthreads();
    }
    if (tid == 0) out[4194304] = BETA * red[0] / 4194304.0f;
}

extern "C" void kernel_launch(void* const* d_in, const int* in_sizes, int n_in,
                              void* d_out, int out_size, void* d_ws, size_t ws_size,
                              hipStream_t stream) {
    const float* z   = (const float*)d_in[0];
    const float* emb = (const float*)d_in[1];
    float* out = (float*)d_out;
    char* wsb = (char*)d_ws;

    float* cst       = (float*)(wsb + CST_OFF);
    int*   cnt       = (int*)(wsb + CNT_OFF);
    float* diff_part = (float*)(wsb + DIFF_OFF);
    float* zmax_part = (float*)(wsb + ZMAX_OFF);
    float* emaxl     = (float*)(wsb + EMAXL_OFF);
    float* emaxe     = (float*)(wsb + EMAXE_OFF);
    float* e2        = (float*)(wsb + E2_OFF);
    int*   bestn     = (int*)(wsb + BESTN_OFF);
    int*   pcnt      = (int*)(wsb + PCNT_OFF);
    int*   plist     = (int*)(wsb + PLIST_OFF);
    int*   candIdx   = (int*)(wsb + CIDX_OFF);
    float* ce2       = (float*)(wsb + CE2_OFF);
    float* zsumP     = (float*)(wsb + ZS_OFF);
    u16*   zh        = (u16*)(wsb + ZH_OFF);
    u16*   ehc       = (u16*)(wsb + EHC_OFF);

    k_split_e<<<2048, 256, 0, stream>>>(emb, e2, emaxl, emaxe);
    k_split_z<<<1024, 256, 0, stream>>>(z, zh, zmax_part, zsumP);
    k_scalars<<<1, 256, 0, stream>>>(zsumP, zmax_part, emaxl, emaxe, e2, cst, cnt);
    k_select<<<64, 256, 0, stream>>>(e2, cst, candIdx, cnt, pcnt);
    k_gather<<<64, 256, 0, stream>>>(emb, e2, cst, cnt, candIdx, ehc, ce2);
    k_cmfma<<<128, 256, 0, stream>>>(zh, ehc, ce2, cst, cnt, pcnt, plist);
    k_exact<<<256, 256, 0, stream>>>(z, emb, e2, cst, cnt, pcnt, plist, candIdx, bestn);
    k_emit<<<256, 256, 0, stream>>>(z, emb, cst, bestn, out, diff_part);
    k_diff<<<1, 256, 0, stream>>>(diff_part, out);
}

// Round 8
// 189.386 us; speedup vs baseline: 2.3764x; 1.0917x over previous
//
#include <hip/hip_runtime.h>
#include <hip/hip_fp16.h>
#include <math.h>

#define FIXLEN 30.0f
#define BETA   0.25f

typedef unsigned short u16;
typedef unsigned int   u32;
typedef unsigned long long u64;
typedef _Float16 half8 __attribute__((ext_vector_type(8)));
typedef float    f32x4 __attribute__((ext_vector_type(4)));

// ---------------- ws layout (bytes) ----------------
#define CST_OFF    512       // f[16]: 0=scale,1=inv_s,2=EPS2,3=maxNrm,4=T_cut
#define CNT_OFF    576       // i[2]: 0=queue cnt, 1=cand cnt
#define DIFF_OFF   1024      // f[256]
#define ZMAX_OFF   2048      // f[1024]
#define EMAXL_OFF  6144      // f[2048]
#define EMAXE_OFF  14336     // f[2048]
#define E2_OFF     22528     // f[16384] -> 88064
#define BESTN_OFF  88064     // i[16384] -> 153600
#define PCNT_OFF   153600    // i[16384] -> 219136
#define PLIST_OFF  219136    // i[16384*8] -> 743424
#define CIDX_OFF   743424    // i[16384] -> 808960
#define CE2_OFF    808960    // f[16384] -> 874496
#define LIST2_OFF  874496    // i[16384] queue of pc>=2 tokens -> 940032
#define ZS_OFF     1048576   // f[4*16384] z^2 partials -> 1310720
#define ZH_OFF     1792000   // half[16384*256] -> 10180608
#define EHC_OFF    10180608  // half[16384*256] gathered candidate plane -> 18569216

__device__ inline void gl_lds16(const void* g, void* l) {
    __builtin_amdgcn_global_load_lds(
        (const __attribute__((address_space(1))) unsigned int*)g,
        (__attribute__((address_space(3))) unsigned int*)l, 16, 0, 0);
}

// ---------------- K1: emb -> e2 + residual-norm maxes ----------------
__global__ void k_split_e(const float* __restrict__ emb, float* __restrict__ e2,
                          float* __restrict__ emaxl, float* __restrict__ emaxe) {
    int gidx = blockIdx.x * 256 + threadIdx.x;   // grid = 2048
    int n = gidx >> 5;
    int c8 = (gidx & 31) * 8;
    const float* ep = emb + (size_t)n * 256 + c8;
    float4 v0 = *(const float4*)ep;
    float4 v1 = *(const float4*)(ep + 4);
    float vv[8] = {v0.x, v0.y, v0.z, v0.w, v1.x, v1.y, v1.z, v1.w};
    float s2 = 0.f, r2 = 0.f;
    #pragma unroll
    for (int k = 0; k < 8; ++k) {
        __half h = __float2half(vv[k]);
        float r = vv[k] - __half2float(h);
        s2 = fmaf(vv[k], vv[k], s2);
        r2 = fmaf(r, r, r2);
    }
    #pragma unroll
    for (int off = 16; off > 0; off >>= 1) {
        s2 += __shfl_down(s2, off, 32);
        r2 += __shfl_down(r2, off, 32);
    }
    __shared__ float L1[8], L2[8];
    if ((threadIdx.x & 31) == 0) {
        e2[n] = s2;
        L1[threadIdx.x >> 5] = r2;
        L2[threadIdx.x >> 5] = s2;
    }
    __syncthreads();
    if (threadIdx.x == 0) {
        float a = 0.f, bmax = 0.f;
        #pragma unroll
        for (int i = 0; i < 8; ++i) { a = fmaxf(a, L1[i]); bmax = fmaxf(bmax, L2[i]); }
        emaxl[blockIdx.x] = a;
        emaxe[blockIdx.x] = bmax;
    }
}

// ---------------- K2: z -> fp16(-2*z/30) plane (transpose) + residual max + z^2 partials ------
__global__ void k_split_z(const float* __restrict__ z, u16* __restrict__ zh,
                          float* __restrict__ zmax_part, float* __restrict__ zsumP) {
    int bi = blockIdx.x;                     // grid = 1024
    int b = bi >> 6, rest = bi & 63;
    int c0 = (rest >> 4) * 64, s0 = (rest & 15) * 64;
    __shared__ float ld[64][65];
    __shared__ float red2[64][4];
    __shared__ float redz[64][4];
    __shared__ float rmax[64];
    int tid = threadIdx.x;
    #pragma unroll
    for (int p = 0; p < 16; ++p) {
        int idx = p * 256 + tid;
        int cc = idx >> 6, ss = idx & 63;
        ld[cc][ss] = z[(size_t)b * 262144 + (size_t)(c0 + cc) * 1024 + s0 + ss];
    }
    __syncthreads();
    int ss2 = tid >> 2, cq = tid & 3;
    int t = b * 1024 + s0 + ss2;
    float r2 = 0.f, zacc = 0.f;
    u32 pk[8];
    #pragma unroll
    for (int k = 0; k < 8; ++k) pk[k] = 0;
    #pragma unroll
    for (int j = 0; j < 16; ++j) {
        float raw = ld[cq * 16 + j][ss2];
        zacc = fmaf(raw, raw, zacc);
        float v = raw * (1.0f / 30.0f);
        __half h = __float2half(v);
        float vh = __half2float(h);
        float r = v - vh;
        r2 = fmaf(r, r, r2);
        __half hs = __float2half(-2.0f * vh);   // exact power-of-2 scale
        pk[j >> 1] |= ((u32)__half_as_ushort(hs)) << ((j & 1) * 16);
    }
    u16* dst = zh + (size_t)t * 256 + c0 + cq * 16;
    *(uint4*)dst = make_uint4(pk[0], pk[1], pk[2], pk[3]);
    *(uint4*)(dst + 8) = make_uint4(pk[4], pk[5], pk[6], pk[7]);
    red2[ss2][cq] = r2;
    redz[ss2][cq] = zacc;
    __syncthreads();
    if (tid < 64) {
        rmax[tid] = red2[tid][0] + red2[tid][1] + red2[tid][2] + red2[tid][3];
        zsumP[(size_t)(rest >> 4) * 16384 + b * 1024 + s0 + tid] =
            redz[tid][0] + redz[tid][1] + redz[tid][2] + redz[tid][3];
    }
    __syncthreads();
    for (int off = 32; off > 0; off >>= 1) {
        if (tid < off) rmax[tid] = fmaxf(rmax[tid], rmax[tid + off]);
        __syncthreads();
    }
    if (tid == 0) zmax_part[bi] = rmax[0];
}

// ---------------- K3: scalars: scale + EPS2 + T_cut ----------------
__global__ void k_scalars(const float* __restrict__ zsumP, const float* __restrict__ zmax_part,
                          const float* __restrict__ emaxl, const float* __restrict__ emaxe,
                          const float* __restrict__ e2, float* __restrict__ cst,
                          int* __restrict__ cnt) {
    int tid = threadIdx.x;  // 256
    float s = 0.f, m = 0.f;
    for (int i = tid; i < 16384; i += 256) {
        float t = zsumP[i] + zsumP[16384 + i] + zsumP[32768 + i] + zsumP[49152 + i];
        float nrm = sqrtf(t);
        s += nrm;
        m = fmaxf(m, nrm);
    }
    float zm = 0.f, el = 0.f, ee = 0.f;
    for (int i = tid; i < 1024; i += 256) zm = fmaxf(zm, zmax_part[i]);
    for (int i = tid; i < 2048; i += 256) { el = fmaxf(el, emaxl[i]); ee = fmaxf(ee, emaxe[i]); }
    __shared__ float S[256], M[256], Z[256], L[256], E[256];
    __shared__ float shv[3];   // inv_s, maxA, EPS2
    S[tid] = s; M[tid] = m; Z[tid] = zm; L[tid] = el; E[tid] = ee;
    __syncthreads();
    for (int off = 128; off > 0; off >>= 1) {
        if (tid < off) {
            S[tid] += S[tid + off];
            M[tid] = fmaxf(M[tid], M[tid + off]);
            Z[tid] = fmaxf(Z[tid], Z[tid + off]);
            L[tid] = fmaxf(L[tid], L[tid + off]);
            E[tid] = fmaxf(E[tid], E[tid + off]);
        }
        __syncthreads();
    }
    if (tid == 0) {
        float pre_len = S[0] * (1.0f / 16384.0f);
        float scale = (pre_len >= FIXLEN) ? (FIXLEN / pre_len) : 1.0f;
        cst[0] = scale;
        cst[1] = 1.0f / scale;
        cst[3] = M[0];
        float maxA  = M[0] * (1.0f / 30.0f);
        float maxEl = sqrtf(L[0]);
        float maxE  = sqrtf(E[0]);
        float maxZl = 2.0f * sqrtf(Z[0]);
        float eps = 2.0f * (maxA * maxEl + maxZl * maxE + maxZl * maxEl) + 0.03f;
        cst[2] = 2.0f * eps;
        cnt[0] = 0;
        cnt[1] = 0;
        shv[0] = 1.0f / scale;
        shv[1] = maxA;
        shv[2] = 2.0f * eps;
    }
    __syncthreads();
    float inv_s = shv[0], maxA = shv[1];
    float tmin = 3.4e38f;
    for (int i = tid; i < 16384; i += 256) {
        float v = e2[i];
        float ub = fmaf(2.0f * maxA, sqrtf(v), v * inv_s);
        tmin = fminf(tmin, ub);
    }
    S[tid] = tmin;
    __syncthreads();
    for (int off = 128; off > 0; off >>= 1) {
        if (tid < off) S[tid] = fminf(S[tid], S[tid + off]);
        __syncthreads();
    }
    if (tid == 0) cst[4] = S[0] + 2.0f * shv[2] + 1.0f;   // T_cut
}

// ---------------- K4: candidate selection ----------------
__global__ void k_select(const float* __restrict__ e2, const float* __restrict__ cst,
                         int* __restrict__ candIdx, int* __restrict__ cnt) {
    int n = blockIdx.x * 256 + threadIdx.x;   // grid 64
    float inv_s = cst[1], maxA = cst[3] * (1.0f / 30.0f), Tc = cst[4];
    float v = e2[n];
    float lb = fmaf(-2.0f * maxA, sqrtf(v), v * inv_s);
    bool sel = lb <= Tc;
    u64 mask = __ballot(sel);
    if (mask) {
        int lane = threadIdx.x & 63;
        int leader = __ffsll((long long)mask) - 1;
        int base = 0;
        if (lane == leader) base = atomicAdd(cnt + 1, __popcll(mask));
        base = __shfl(base, leader);
        if (sel) {
            int rank = __popcll(mask & ((1ull << lane) - 1ull));
            candIdx[base + rank] = n;
        }
    }
}

// ---------------- K5: gather candidate rows -> fp16 plane + scaled e2 (pad to 256-mult) -------
__global__ void k_gather(const float* __restrict__ emb, const float* __restrict__ e2,
                         const float* __restrict__ cst, const int* __restrict__ cnt,
                         const int* __restrict__ candIdx, u16* __restrict__ ehc,
                         float* __restrict__ ce2) {
    int w = threadIdx.x >> 6, lane = threadIdx.x & 63;
    int wid = blockIdx.x * 4 + w;   // grid 64 -> 256 waves
    int C = cnt[1];
    int NP = (C + 255) & ~255;
    float inv_s = cst[1];
    for (int slot = wid; slot < NP; slot += 256) {
        if (slot < C) {
            int n = candIdx[slot];
            float4 v = *(const float4*)&emb[(size_t)n * 256 + lane * 4];
            u32 p0 = (u32)__half_as_ushort(__float2half(v.x)) |
                     ((u32)__half_as_ushort(__float2half(v.y)) << 16);
            u32 p1 = (u32)__half_as_ushort(__float2half(v.z)) |
                     ((u32)__half_as_ushort(__float2half(v.w)) << 16);
            *(uint2*)&ehc[(size_t)slot * 256 + lane * 4] = make_uint2(p0, p1);
            if (lane == 0) ce2[slot] = e2[n] * inv_s;
        } else {
            *(uint2*)&ehc[(size_t)slot * 256 + lane * 4] = make_uint2(0u, 0u);
            if (lane == 0) ce2[slot] = 3.0e37f;   // pad: never near the min
        }
    }
}

// ---------------- K6: candidate GEMM, 32 tok/block, two-pass, LDS pair lists ------------------
// grid 512 (2-3 blocks/CU -> chains overlap).  4 waves: wave w owns col group w*64 of each
// 256-cand chunk; all waves share the 32 token rows (acc[2][4]).  Pass 1: per-token min d1.
// Pass 2: bitwise-identical recompute, emit (token, slot) with d_fp16 <= d1+EPS2+eps into LDS
// lists.  Finalize: pc==1 -> write bestn directly; pc>=2 -> enqueue token + spill list.
__launch_bounds__(256, 2)
__global__ void k_cmfma(const u16* __restrict__ zh, const u16* __restrict__ ehc,
                        const float* __restrict__ ce2, const float* __restrict__ cst,
                        int* __restrict__ cnt, const int* __restrict__ candIdx,
                        int* __restrict__ pcnt, int* __restrict__ plist,
                        int* __restrict__ list2, int* __restrict__ bestn) {
    __shared__ __align__(16) char lds[51200];
    char* sAb = lds;                        // 16 KB: [32 rows][32 slots16], slot^=(row&7) low3
    char* sB0 = lds + 16384;                // 16 KB: [256 rows][4 slots16], slot^=((row>>1)&3)
    char* sB1 = lds + 32768;                // 16 KB
    float* d1buf  = (float*)(lds + 49152);  // [4][32]
    float* limitS = (float*)(lds + 49664);  // [32]
    int*   pcnts  = (int*)(lds + 49792);    // [32]
    int*   pls    = (int*)(lds + 49920);    // [32][8]

    int t0 = blockIdx.x * 32;               // grid = 512
    int C = cnt[1];
    int nch = (C + 255) >> 8;
    float THR = cst[2] + 0.0625f;           // EPS2 + slack (extra emission is always sound)
    int tid = threadIdx.x, w = tid >> 6, lane = tid & 63;
    int ml = lane & 15, q = lane >> 4;
    int wn0 = w * 64;
    int x7 = ml & 7;
    int xb = (ml >> 1) & 3;
    int slB = q ^ xb;

    // prologue: stage A plane (4 granules/thread), source-XOR swizzle
    #pragma unroll
    for (int i = 0; i < 4; ++i) {
        int el = i * 256 + tid;
        int row = el >> 5, j = el & 31;
        int jsrc = (j & 24) | ((j & 7) ^ (row & 7));
        gl_lds16(zh + (size_t)(t0 + row) * 256 + jsrc * 8, sAb + el * 16);
    }
    // prologue: stage B chunk0 slice0 -> sB0 (4 granules/thread)
    #pragma unroll
    for (int i = 0; i < 4; ++i) {
        int el = i * 256 + tid;
        int row = el >> 2, j = el & 3;
        int jsrc = j ^ ((row >> 1) & 3);
        gl_lds16(ehc + (size_t)row * 256 + jsrc * 8, sB0 + el * 16);
    }

    float b1[8];
    #pragma unroll
    for (int k = 0; k < 8; ++k) b1[k] = 3.4e38f;

    // ---------------- pass 1: per-token min ----------------
    #pragma unroll 1
    for (int c = 0; c < nch; ++c) {
        float etb[4];
        #pragma unroll
        for (int tj = 0; tj < 4; ++tj) etb[tj] = ce2[c * 256 + wn0 + tj * 16 + ml];
        f32x4 acc[2][4];
        #pragma unroll
        for (int ti = 0; ti < 2; ++ti)
            #pragma unroll
            for (int tj = 0; tj < 4; ++tj)
                acc[ti][tj] = (f32x4){etb[tj], etb[tj], etb[tj], etb[tj]};
        #pragma unroll
        for (int s = 0; s < 8; ++s) {
            __syncthreads();
            if (s < 7 || c + 1 < nch) {
                int s2 = (s + 1) & 7;
                int cc2 = (s == 7) ? (c + 1) : c;
                char* dst = (s & 1) ? sB0 : sB1;
                #pragma unroll
                for (int i = 0; i < 4; ++i) {
                    int el = i * 256 + tid;
                    int row = el >> 2, j = el & 3;
                    int jsrc = j ^ ((row >> 1) & 3);
                    gl_lds16(ehc + (size_t)(cc2 * 256 + row) * 256 + s2 * 32 + jsrc * 8,
                             dst + el * 16);
                }
            }
            __builtin_amdgcn_sched_barrier(0);
            const char* sB = (s & 1) ? sB1 : sB0;
            half8 A[2], B[4];
            #pragma unroll
            for (int tj = 0; tj < 4; ++tj)
                B[tj] = *(const half8*)(sB + (wn0 + tj * 16 + ml) * 64 + slB * 16);
            int slotA = (s >> 1) * 8 + ((((s & 1) * 4) + q) ^ x7);
            #pragma unroll
            for (int ti = 0; ti < 2; ++ti)
                A[ti] = *(const half8*)(sAb + (ti * 16 + ml) * 512 + slotA * 16);
            #pragma unroll
            for (int ti = 0; ti < 2; ++ti)
                #pragma unroll
                for (int tj = 0; tj < 4; ++tj)
                    acc[ti][tj] = __builtin_amdgcn_mfma_f32_16x16x32_f16(A[ti], B[tj], acc[ti][tj], 0, 0, 0);
        }
        #pragma unroll
        for (int ti = 0; ti < 2; ++ti)
            #pragma unroll
            for (int r = 0; r < 4; ++r)
                #pragma unroll
                for (int tj = 0; tj < 4; ++tj)
                    b1[ti * 4 + r] = fminf(b1[ti * 4 + r], acc[ti][tj][r]);
    }

    // merge: cross-lane over ml, then cross-wave via LDS
    #pragma unroll
    for (int k = 0; k < 8; ++k) {
        #pragma unroll
        for (int m = 1; m < 16; m <<= 1)
            b1[k] = fminf(b1[k], __shfl_xor(b1[k], m));
    }
    __syncthreads();
    if (ml == 0) {
        #pragma unroll
        for (int ti = 0; ti < 2; ++ti)
            #pragma unroll
            for (int r = 0; r < 4; ++r)
                d1buf[w * 32 + ti * 16 + q * 4 + r] = b1[ti * 4 + r];
    }
    __syncthreads();
    if (tid < 32) {
        float d = fminf(fminf(d1buf[tid], d1buf[32 + tid]),
                        fminf(d1buf[64 + tid], d1buf[96 + tid]));
        limitS[tid] = d + THR;
        pcnts[tid] = 0;
    }
    __syncthreads();
    float limit[8];
    #pragma unroll
    for (int ti = 0; ti < 2; ++ti)
        #pragma unroll
        for (int r = 0; r < 4; ++r)
            limit[ti * 4 + r] = limitS[ti * 16 + q * 4 + r];
    __syncthreads();

    // ---------------- pass 2: identical recompute + emit ----------------
    #pragma unroll
    for (int i = 0; i < 4; ++i) {
        int el = i * 256 + tid;
        int row = el >> 2, j = el & 3;
        int jsrc = j ^ ((row >> 1) & 3);
        gl_lds16(ehc + (size_t)row * 256 + jsrc * 8, sB0 + el * 16);
    }
    #pragma unroll 1
    for (int c = 0; c < nch; ++c) {
        float etb[4];
        #pragma unroll
        for (int tj = 0; tj < 4; ++tj) etb[tj] = ce2[c * 256 + wn0 + tj * 16 + ml];
        f32x4 acc[2][4];
        #pragma unroll
        for (int ti = 0; ti < 2; ++ti)
            #pragma unroll
            for (int tj = 0; tj < 4; ++tj)
                acc[ti][tj] = (f32x4){etb[tj], etb[tj], etb[tj], etb[tj]};
        #pragma unroll
        for (int s = 0; s < 8; ++s) {
            __syncthreads();
            if (s < 7 || c + 1 < nch) {
                int s2 = (s + 1) & 7;
                int cc2 = (s == 7) ? (c + 1) : c;
                char* dst = (s & 1) ? sB0 : sB1;
                #pragma unroll
                for (int i = 0; i < 4; ++i) {
                    int el = i * 256 + tid;
                    int row = el >> 2, j = el & 3;
                    int jsrc = j ^ ((row >> 1) & 3);
                    gl_lds16(ehc + (size_t)(cc2 * 256 + row) * 256 + s2 * 32 + jsrc * 8,
                             dst + el * 16);
                }
            }
            __builtin_amdgcn_sched_barrier(0);
            const char* sB = (s & 1) ? sB1 : sB0;
            half8 A[2], B[4];
            #pragma unroll
            for (int tj = 0; tj < 4; ++tj)
                B[tj] = *(const half8*)(sB + (wn0 + tj * 16 + ml) * 64 + slB * 16);
            int slotA = (s >> 1) * 8 + ((((s & 1) * 4) + q) ^ x7);
            #pragma unroll
            for (int ti = 0; ti < 2; ++ti)
                A[ti] = *(const half8*)(sAb + (ti * 16 + ml) * 512 + slotA * 16);
            #pragma unroll
            for (int ti = 0; ti < 2; ++ti)
                #pragma unroll
                for (int tj = 0; tj < 4; ++tj)
                    acc[ti][tj] = __builtin_amdgcn_mfma_f32_16x16x32_f16(A[ti], B[tj], acc[ti][tj], 0, 0, 0);
        }
        int slot0 = c * 256 + wn0 + ml;
        #pragma unroll
        for (int ti = 0; ti < 2; ++ti) {
            #pragma unroll
            for (int r = 0; r < 4; ++r) {
                int k = ti * 4 + r;
                int row = ti * 16 + q * 4 + r;
                #pragma unroll
                for (int tj = 0; tj < 4; ++tj) {
                    if (acc[ti][tj][r] <= limit[k]) {
                        int pos = atomicAdd(&pcnts[row], 1);
                        if (pos < 8) pls[row * 8 + pos] = slot0 + tj * 16;
                    }
                }
            }
        }
    }
    __syncthreads();
    // finalize: pc==1 -> bestn; pc>=2 -> enqueue
    if (tid < 32) {
        int t = t0 + tid;
        int pc = pcnts[tid];
        if (pc == 1) {
            bestn[t] = candIdx[pls[tid * 8]];
        } else {
            int pos = atomicAdd(cnt, 1);
            list2[pos] = t;
            pcnt[t] = pc;
            int mm = pc < 8 ? pc : 8;
            for (int i = 0; i < mm; ++i) plist[t * 8 + i] = pls[tid * 8 + i];
        }
    }
}

// ---------------- K7: exact fp32 eval of queued tokens, one wave each ----------------
__global__ void k_exact(const float* __restrict__ z, const float* __restrict__ emb,
                        const float* __restrict__ e2, const float* __restrict__ cst,
                        const int* __restrict__ cnt, const int* __restrict__ pcnt,
                        const int* __restrict__ plist, const int* __restrict__ candIdx,
                        const int* __restrict__ list2, int* __restrict__ bestn) {
    int w = threadIdx.x >> 6, lane = threadIdx.x & 63;
    int wid = blockIdx.x * 4 + w;              // grid 256 -> 1024 waves
    int NQ = cnt[0], C = cnt[1];
    float inv_s = cst[1];
    for (int it = wid; it < NQ; it += 1024) {
        int t = list2[it];
        int b = t >> 10, hw = t & 1023;
        const float* zb = z + (size_t)b * 262144 + hw;
        float4 a4;
        a4.x = zb[(size_t)(lane * 4 + 0) << 10] * (1.0f / 30.0f);
        a4.y = zb[(size_t)(lane * 4 + 1) << 10] * (1.0f / 30.0f);
        a4.z = zb[(size_t)(lane * 4 + 2) << 10] * (1.0f / 30.0f);
        a4.w = zb[(size_t)(lane * 4 + 3) << 10] * (1.0f / 30.0f);
        int pc = pcnt[t];
        float bestv = 3.4e38f; int bi = 0x7fffffff;
        if (pc <= 8) {
            for (int i = 0; i < pc; ++i) {
                int n = candIdx[plist[t * 8 + i]];
                float4 e4 = *(const float4*)&emb[(size_t)n * 256 + lane * 4];
                float s = a4.x * e4.x + a4.y * e4.y + a4.z * e4.z + a4.w * e4.w;
                #pragma unroll
                for (int m = 1; m < 64; m <<= 1) s += __shfl_xor(s, m);
                float d = fmaf(-2.0f, s, e2[n] * inv_s);
                if (d < bestv || (d == bestv && n < bi)) { bestv = d; bi = n; }
            }
        } else {
            for (int slot = 0; slot < C; ++slot) {
                int n = candIdx[slot];
                float4 e4 = *(const float4*)&emb[(size_t)n * 256 + lane * 4];
                float s = a4.x * e4.x + a4.y * e4.y + a4.z * e4.z + a4.w * e4.w;
                #pragma unroll
                for (int m = 1; m < 64; m <<= 1) s += __shfl_xor(s, m);
                float d = fmaf(-2.0f, s, e2[n] * inv_s);
                if (d < bestv || (d == bestv && n < bi)) { bestv = d; bi = n; }
            }
        }
        if (lane == 0) bestn[t] = bi;
    }
}

// ---------------- K8: emit z_q, idx, diff partials ----------------
__global__ void k_emit(const float* __restrict__ z, const float* __restrict__ emb,
                       const float* __restrict__ cst, const int* __restrict__ bestn,
                       float* __restrict__ out, float* __restrict__ diff_part) {
    int blk = blockIdx.x;                 // 256
    int cq = blk >> 6, sub = blk & 63;
    int b = sub >> 2;
    int tl = (sub & 3) * 256 + threadIdx.x;
    int t = b * 1024 + tl;
    int bi = bestn[t];
    if (cq == 0) out[4194305 + t] = (float)bi;
    float scale = cst[0];
    const float* er = emb + (size_t)bi * 256 + cq * 64;
    const float* zr = z + (size_t)b * 262144 + (size_t)cq * 65536 + tl;
    float* orow = out + (size_t)b * 262144 + (size_t)cq * 65536 + tl;
    float ds = 0.f;
    #pragma unroll 8
    for (int j = 0; j < 64; ++j) {
        float qv = er[j] * FIXLEN;
        float zt = zr[(size_t)j << 10] * scale;
        float dd = qv - zt;
        ds = fmaf(dd, dd, ds);
        orow[(size_t)j << 10] = qv;
    }
    __shared__ float red[256];
    red[threadIdx.x] = ds;
    __syncthreads();
    for (int off = 128; off > 0; off >>= 1) {
        if (threadIdx.x < off) red[threadIdx.x] += red[threadIdx.x + off];
        __syncthreads();
    }
    if (threadIdx.x == 0) diff_part[blk] = red[0];
}

// ---------------- K9: finalize diff ----------------
__global__ void k_diff(const float* __restrict__ diff_part, float* __restrict__ out) {
    int tid = threadIdx.x;   // 256
    __shared__ float red[256];
    red[tid] = diff_part[tid];
    __syncthreads();
    for (int off = 128; off > 0; off >>= 1) {
        if (tid < off) red[tid] += red[tid + off];
        __syncthreads();
    }
    if (tid == 0) out[4194304] = BETA * red[0] / 4194304.0f;
}

extern "C" void kernel_launch(void* const* d_in, const int* in_sizes, int n_in,
                              void* d_out, int out_size, void* d_ws, size_t ws_size,
                              hipStream_t stream) {
    const float* z   = (const float*)d_in[0];
    const float* emb = (const float*)d_in[1];
    float* out = (float*)d_out;
    char* wsb = (char*)d_ws;

    float* cst       = (float*)(wsb + CST_OFF);
    int*   cnt       = (int*)(wsb + CNT_OFF);
    float* diff_part = (float*)(wsb + DIFF_OFF);
    float* zmax_part = (float*)(wsb + ZMAX_OFF);
    float* emaxl     = (float*)(wsb + EMAXL_OFF);
    float* emaxe     = (float*)(wsb + EMAXE_OFF);
    float* e2        = (float*)(wsb + E2_OFF);
    int*   bestn     = (int*)(wsb + BESTN_OFF);
    int*   pcnt      = (int*)(wsb + PCNT_OFF);
    int*   plist     = (int*)(wsb + PLIST_OFF);
    int*   candIdx   = (int*)(wsb + CIDX_OFF);
    float* ce2       = (float*)(wsb + CE2_OFF);
    int*   list2     = (int*)(wsb + LIST2_OFF);
    float* zsumP     = (float*)(wsb + ZS_OFF);
    u16*   zh        = (u16*)(wsb + ZH_OFF);
    u16*   ehc       = (u16*)(wsb + EHC_OFF);

    k_split_e<<<2048, 256, 0, stream>>>(emb, e2, emaxl, emaxe);
    k_split_z<<<1024, 256, 0, stream>>>(z, zh, zmax_part, zsumP);
    k_scalars<<<1, 256, 0, stream>>>(zsumP, zmax_part, emaxl, emaxe, e2, cst, cnt);
    k_select<<<64, 256, 0, stream>>>(e2, cst, candIdx, cnt);
    k_gather<<<64, 256, 0, stream>>>(emb, e2, cst, cnt, candIdx, ehc, ce2);
    k_cmfma<<<512, 256, 0, stream>>>(zh, ehc, ce2, cst, cnt, candIdx, pcnt, plist, list2, bestn);
    k_exact<<<256, 256, 0, stream>>>(z, emb, e2, cst, cnt, pcnt, plist, candIdx, list2, bestn);
    k_emit<<<256, 256, 0, stream>>>(z, emb, cst, bestn, out, diff_part);
    k_diff<<<1, 256, 0, stream>>>(diff_part, out);
}

// Round 9
// 156.973 us; speedup vs baseline: 2.8672x; 1.2065x over previous
//
#include <hip/hip_runtime.h>
#include <hip/hip_fp16.h>
#include <math.h>

#define FIXLEN 30.0f
#define BETA   0.25f

typedef unsigned short u16;
typedef unsigned int   u32;
typedef unsigned long long u64;
typedef _Float16 half8 __attribute__((ext_vector_type(8)));
typedef float    f32x4 __attribute__((ext_vector_type(4)));

// ---------------- ws layout (bytes) ----------------
#define NRM_OFF    0         // f[64] per-block norm-sum partials
#define NRMX_OFF   256       // f[64] per-block norm-max partials
#define CST_OFF    512       // f[16]: 0=scale,1=inv_s,2=EPS2,3=maxNrm,4=T_cut
#define CNT_OFF    576       // i[2]: 0=queue cnt, 1=cand cnt
#define DIFF_OFF   1024      // f[256]
#define ZMAX_OFF   2048      // f[1024]
#define EMAXL_OFF  6144      // f[2048]
#define EMAXE_OFF  14336     // f[2048]
#define E2_OFF     22528     // f[16384] -> 88064
#define BESTN_OFF  88064     // i[16384] -> 153600
#define PCNT_OFF   153600    // i[16384] -> 219136
#define PLIST_OFF  219136    // i[16384*8] -> 743424
#define CIDX_OFF   743424    // i[16384] -> 808960
#define CE2_OFF    808960    // f[16384] -> 874496
#define LIST2_OFF  874496    // i[16384] queue of pc>=2 tokens -> 940032
#define E2MIN_OFF  940032    // f[2048] per-block e2-min partials -> 948224
#define ZS_OFF     1048576   // f[4*16384] z^2 partials -> 1310720
#define ZH_OFF     1792000   // half[16384*256] -> 10180608
#define EHC_OFF    10180608  // half[16384*256] gathered candidate plane -> 18569216

__device__ inline void gl_lds16(const void* g, void* l) {
    __builtin_amdgcn_global_load_lds(
        (const __attribute__((address_space(1))) unsigned int*)g,
        (__attribute__((address_space(3))) unsigned int*)l, 16, 0, 0);
}

// ---------------- K1: emb -> e2 + residual-norm maxes + e2-min partials ----------------
__global__ void k_split_e(const float* __restrict__ emb, float* __restrict__ e2,
                          float* __restrict__ emaxl, float* __restrict__ emaxe,
                          float* __restrict__ e2minp) {
    int gidx = blockIdx.x * 256 + threadIdx.x;   // grid = 2048
    int n = gidx >> 5;
    int c8 = (gidx & 31) * 8;
    const float* ep = emb + (size_t)n * 256 + c8;
    float4 v0 = *(const float4*)ep;
    float4 v1 = *(const float4*)(ep + 4);
    float vv[8] = {v0.x, v0.y, v0.z, v0.w, v1.x, v1.y, v1.z, v1.w};
    float s2 = 0.f, r2 = 0.f;
    #pragma unroll
    for (int k = 0; k < 8; ++k) {
        __half h = __float2half(vv[k]);
        float r = vv[k] - __half2float(h);
        s2 = fmaf(vv[k], vv[k], s2);
        r2 = fmaf(r, r, r2);
    }
    #pragma unroll
    for (int off = 16; off > 0; off >>= 1) {
        s2 += __shfl_down(s2, off, 32);
        r2 += __shfl_down(r2, off, 32);
    }
    __shared__ float L1[8], L2[8];
    if ((threadIdx.x & 31) == 0) {
        e2[n] = s2;
        L1[threadIdx.x >> 5] = r2;
        L2[threadIdx.x >> 5] = s2;
    }
    __syncthreads();
    if (threadIdx.x == 0) {
        float a = 0.f, bmax = 0.f, bmin = 3.4e38f;
        #pragma unroll
        for (int i = 0; i < 8; ++i) {
            a = fmaxf(a, L1[i]);
            bmax = fmaxf(bmax, L2[i]);
            bmin = fminf(bmin, L2[i]);
        }
        emaxl[blockIdx.x] = a;
        emaxe[blockIdx.x] = bmax;
        e2minp[blockIdx.x] = bmin;
    }
}

// ---------------- K2: z -> fp16(-2*z/30) plane (transpose) + residual max + z^2 partials ------
__global__ void k_split_z(const float* __restrict__ z, u16* __restrict__ zh,
                          float* __restrict__ zmax_part, float* __restrict__ zsumP) {
    int bi = blockIdx.x;                     // grid = 1024
    int b = bi >> 6, rest = bi & 63;
    int c0 = (rest >> 4) * 64, s0 = (rest & 15) * 64;
    __shared__ float ld[64][65];
    __shared__ float red2[64][4];
    __shared__ float redz[64][4];
    __shared__ float rmax[64];
    int tid = threadIdx.x;
    #pragma unroll
    for (int p = 0; p < 16; ++p) {
        int idx = p * 256 + tid;
        int cc = idx >> 6, ss = idx & 63;
        ld[cc][ss] = z[(size_t)b * 262144 + (size_t)(c0 + cc) * 1024 + s0 + ss];
    }
    __syncthreads();
    int ss2 = tid >> 2, cq = tid & 3;
    int t = b * 1024 + s0 + ss2;
    float r2 = 0.f, zacc = 0.f;
    u32 pk[8];
    #pragma unroll
    for (int k = 0; k < 8; ++k) pk[k] = 0;
    #pragma unroll
    for (int j = 0; j < 16; ++j) {
        float raw = ld[cq * 16 + j][ss2];
        zacc = fmaf(raw, raw, zacc);
        float v = raw * (1.0f / 30.0f);
        __half h = __float2half(v);
        float vh = __half2float(h);
        float r = v - vh;
        r2 = fmaf(r, r, r2);
        __half hs = __float2half(-2.0f * vh);   // exact power-of-2 scale
        pk[j >> 1] |= ((u32)__half_as_ushort(hs)) << ((j & 1) * 16);
    }
    u16* dst = zh + (size_t)t * 256 + c0 + cq * 16;
    *(uint4*)dst = make_uint4(pk[0], pk[1], pk[2], pk[3]);
    *(uint4*)(dst + 8) = make_uint4(pk[4], pk[5], pk[6], pk[7]);
    red2[ss2][cq] = r2;
    redz[ss2][cq] = zacc;
    __syncthreads();
    if (tid < 64) {
        rmax[tid] = red2[tid][0] + red2[tid][1] + red2[tid][2] + red2[tid][3];
        zsumP[(size_t)(rest >> 4) * 16384 + b * 1024 + s0 + tid] =
            redz[tid][0] + redz[tid][1] + redz[tid][2] + redz[tid][3];
    }
    __syncthreads();
    for (int off = 32; off > 0; off >>= 1) {
        if (tid < off) rmax[tid] = fmaxf(rmax[tid], rmax[tid + off]);
        __syncthreads();
    }
    if (tid == 0) zmax_part[bi] = rmax[0];
}

// ---------------- K3: per-token norms -> 64 sum/max partials (grid 64) ----------------
__global__ void k_norm2(const float* __restrict__ zsumP, float* __restrict__ nrm_part,
                        float* __restrict__ nrmx_part) {
    int t = blockIdx.x * 256 + threadIdx.x;   // grid = 64
    float tot = zsumP[t] + zsumP[16384 + t] + zsumP[32768 + t] + zsumP[49152 + t];
    float nrm = sqrtf(tot);
    __shared__ float rs[256], rm[256];
    rs[threadIdx.x] = nrm; rm[threadIdx.x] = nrm;
    __syncthreads();
    for (int off = 128; off > 0; off >>= 1) {
        if (threadIdx.x < off) {
            rs[threadIdx.x] += rs[threadIdx.x + off];
            rm[threadIdx.x] = fmaxf(rm[threadIdx.x], rm[threadIdx.x + off]);
        }
        __syncthreads();
    }
    if (threadIdx.x == 0) { nrm_part[blockIdx.x] = rs[0]; nrmx_part[blockIdx.x] = rm[0]; }
}

// ---------------- K4: scalars from partials only (~7K elements) ----------------
// T = min_n UB(n); UB(e2) = e2*inv_s + 2*maxA*sqrt(e2) is increasing in e2
// -> T = UB(e2min).  +1.0 margin covers all fp32 evaluation differences.
__global__ void k_scalars(const float* __restrict__ nrm_part, const float* __restrict__ nrmx_part,
                          const float* __restrict__ zmax_part, const float* __restrict__ emaxl,
                          const float* __restrict__ emaxe, const float* __restrict__ e2minp,
                          float* __restrict__ cst, int* __restrict__ cnt) {
    int tid = threadIdx.x;  // 256
    float s = (tid < 64) ? nrm_part[tid] : 0.f;
    float m = (tid < 64) ? nrmx_part[tid] : 0.f;
    float zm = 0.f, el = 0.f, ee = 0.f, em = 3.4e38f;
    for (int i = tid; i < 1024; i += 256) zm = fmaxf(zm, zmax_part[i]);
    for (int i = tid; i < 2048; i += 256) {
        el = fmaxf(el, emaxl[i]);
        ee = fmaxf(ee, emaxe[i]);
        em = fminf(em, e2minp[i]);
    }
    __shared__ float S[256], M[256], Z[256], L[256], E[256], Q[256];
    S[tid] = s; M[tid] = m; Z[tid] = zm; L[tid] = el; E[tid] = ee; Q[tid] = em;
    __syncthreads();
    for (int off = 128; off > 0; off >>= 1) {
        if (tid < off) {
            S[tid] += S[tid + off];
            M[tid] = fmaxf(M[tid], M[tid + off]);
            Z[tid] = fmaxf(Z[tid], Z[tid + off]);
            L[tid] = fmaxf(L[tid], L[tid + off]);
            E[tid] = fmaxf(E[tid], E[tid + off]);
            Q[tid] = fminf(Q[tid], Q[tid + off]);
        }
        __syncthreads();
    }
    if (tid == 0) {
        float pre_len = S[0] * (1.0f / 16384.0f);
        float scale = (pre_len >= FIXLEN) ? (FIXLEN / pre_len) : 1.0f;
        float inv_s = 1.0f / scale;
        cst[0] = scale;
        cst[1] = inv_s;
        cst[3] = M[0];
        float maxA  = M[0] * (1.0f / 30.0f);
        float maxEl = sqrtf(L[0]);
        float maxE  = sqrtf(E[0]);
        float maxZl = 2.0f * sqrtf(Z[0]);
        float eps = 2.0f * (maxA * maxEl + maxZl * maxE + maxZl * maxEl) + 0.03f;
        float EPS2 = 2.0f * eps;
        cst[2] = EPS2;
        float e2min = Q[0];
        float T = fmaf(2.0f * maxA, sqrtf(e2min), e2min * inv_s);
        cst[4] = T + 2.0f * EPS2 + 1.0f;   // T_cut
        cnt[0] = 0;
        cnt[1] = 0;
    }
}

// ---------------- K5: candidate selection ----------------
__global__ void k_select(const float* __restrict__ e2, const float* __restrict__ cst,
                         int* __restrict__ candIdx, int* __restrict__ cnt) {
    int n = blockIdx.x * 256 + threadIdx.x;   // grid 64
    float inv_s = cst[1], maxA = cst[3] * (1.0f / 30.0f), Tc = cst[4];
    float v = e2[n];
    float lb = fmaf(-2.0f * maxA, sqrtf(v), v * inv_s);
    bool sel = lb <= Tc;
    u64 mask = __ballot(sel);
    if (mask) {
        int lane = threadIdx.x & 63;
        int leader = __ffsll((long long)mask) - 1;
        int base = 0;
        if (lane == leader) base = atomicAdd(cnt + 1, __popcll(mask));
        base = __shfl(base, leader);
        if (sel) {
            int rank = __popcll(mask & ((1ull << lane) - 1ull));
            candIdx[base + rank] = n;
        }
    }
}

// ---------------- K6: gather candidate rows -> fp16 plane + scaled e2 (pad to 256-mult) -------
__global__ void k_gather(const float* __restrict__ emb, const float* __restrict__ e2,
                         const float* __restrict__ cst, const int* __restrict__ cnt,
                         const int* __restrict__ candIdx, u16* __restrict__ ehc,
                         float* __restrict__ ce2) {
    int w = threadIdx.x >> 6, lane = threadIdx.x & 63;
    int wid = blockIdx.x * 4 + w;   // grid 64 -> 256 waves
    int C = cnt[1];
    int NP = (C + 255) & ~255;
    float inv_s = cst[1];
    for (int slot = wid; slot < NP; slot += 256) {
        if (slot < C) {
            int n = candIdx[slot];
            float4 v = *(const float4*)&emb[(size_t)n * 256 + lane * 4];
            u32 p0 = (u32)__half_as_ushort(__float2half(v.x)) |
                     ((u32)__half_as_ushort(__float2half(v.y)) << 16);
            u32 p1 = (u32)__half_as_ushort(__float2half(v.z)) |
                     ((u32)__half_as_ushort(__float2half(v.w)) << 16);
            *(uint2*)&ehc[(size_t)slot * 256 + lane * 4] = make_uint2(p0, p1);
            if (lane == 0) ce2[slot] = e2[n] * inv_s;
        } else {
            *(uint2*)&ehc[(size_t)slot * 256 + lane * 4] = make_uint2(0u, 0u);
            if (lane == 0) ce2[slot] = 3.0e37f;   // pad: never near the min
        }
    }
}

// ---------------- K7: candidate GEMM, 32 tok/block, two-pass, LDS pair lists ------------------
__launch_bounds__(256, 2)
__global__ void k_cmfma(const u16* __restrict__ zh, const u16* __restrict__ ehc,
                        const float* __restrict__ ce2, const float* __restrict__ cst,
                        int* __restrict__ cnt, const int* __restrict__ candIdx,
                        int* __restrict__ pcnt, int* __restrict__ plist,
                        int* __restrict__ list2, int* __restrict__ bestn) {
    __shared__ __align__(16) char lds[51200];
    char* sAb = lds;                        // 16 KB: [32 rows][32 slots16], slot^=(row&7) low3
    char* sB0 = lds + 16384;                // 16 KB: [256 rows][4 slots16], slot^=((row>>1)&3)
    char* sB1 = lds + 32768;                // 16 KB
    float* d1buf  = (float*)(lds + 49152);  // [4][32]
    float* limitS = (float*)(lds + 49664);  // [32]
    int*   pcnts  = (int*)(lds + 49792);    // [32]
    int*   pls    = (int*)(lds + 49920);    // [32][8]

    int t0 = blockIdx.x * 32;               // grid = 512
    int C = cnt[1];
    int nch = (C + 255) >> 8;
    float THR = cst[2] + 0.0625f;           // EPS2 + slack (extra emission is always sound)
    int tid = threadIdx.x, w = tid >> 6, lane = tid & 63;
    int ml = lane & 15, q = lane >> 4;
    int wn0 = w * 64;
    int x7 = ml & 7;
    int xb = (ml >> 1) & 3;
    int slB = q ^ xb;

    // prologue: stage A plane (4 granules/thread), source-XOR swizzle
    #pragma unroll
    for (int i = 0; i < 4; ++i) {
        int el = i * 256 + tid;
        int row = el >> 5, j = el & 31;
        int jsrc = (j & 24) | ((j & 7) ^ (row & 7));
        gl_lds16(zh + (size_t)(t0 + row) * 256 + jsrc * 8, sAb + el * 16);
    }
    // prologue: stage B chunk0 slice0 -> sB0 (4 granules/thread)
    #pragma unroll
    for (int i = 0; i < 4; ++i) {
        int el = i * 256 + tid;
        int row = el >> 2, j = el & 3;
        int jsrc = j ^ ((row >> 1) & 3);
        gl_lds16(ehc + (size_t)row * 256 + jsrc * 8, sB0 + el * 16);
    }

    float b1[8];
    #pragma unroll
    for (int k = 0; k < 8; ++k) b1[k] = 3.4e38f;

    // ---------------- pass 1: per-token min ----------------
    #pragma unroll 1
    for (int c = 0; c < nch; ++c) {
        float etb[4];
        #pragma unroll
        for (int tj = 0; tj < 4; ++tj) etb[tj] = ce2[c * 256 + wn0 + tj * 16 + ml];
        f32x4 acc[2][4];
        #pragma unroll
        for (int ti = 0; ti < 2; ++ti)
            #pragma unroll
            for (int tj = 0; tj < 4; ++tj)
                acc[ti][tj] = (f32x4){etb[tj], etb[tj], etb[tj], etb[tj]};
        #pragma unroll
        for (int s = 0; s < 8; ++s) {
            __syncthreads();
            if (s < 7 || c + 1 < nch) {
                int s2 = (s + 1) & 7;
                int cc2 = (s == 7) ? (c + 1) : c;
                char* dst = (s & 1) ? sB0 : sB1;
                #pragma unroll
                for (int i = 0; i < 4; ++i) {
                    int el = i * 256 + tid;
                    int row = el >> 2, j = el & 3;
                    int jsrc = j ^ ((row >> 1) & 3);
                    gl_lds16(ehc + (size_t)(cc2 * 256 + row) * 256 + s2 * 32 + jsrc * 8,
                             dst + el * 16);
                }
            }
            __builtin_amdgcn_sched_barrier(0);
            const char* sB = (s & 1) ? sB1 : sB0;
            half8 A[2], B[4];
            #pragma unroll
            for (int tj = 0; tj < 4; ++tj)
                B[tj] = *(const half8*)(sB + (wn0 + tj * 16 + ml) * 64 + slB * 16);
            int slotA = (s >> 1) * 8 + ((((s & 1) * 4) + q) ^ x7);
            #pragma unroll
            for (int ti = 0; ti < 2; ++ti)
                A[ti] = *(const half8*)(sAb + (ti * 16 + ml) * 512 + slotA * 16);
            #pragma unroll
            for (int ti = 0; ti < 2; ++ti)
                #pragma unroll
                for (int tj = 0; tj < 4; ++tj)
                    acc[ti][tj] = __builtin_amdgcn_mfma_f32_16x16x32_f16(A[ti], B[tj], acc[ti][tj], 0, 0, 0);
        }
        #pragma unroll
        for (int ti = 0; ti < 2; ++ti)
            #pragma unroll
            for (int r = 0; r < 4; ++r)
                #pragma unroll
                for (int tj = 0; tj < 4; ++tj)
                    b1[ti * 4 + r] = fminf(b1[ti * 4 + r], acc[ti][tj][r]);
    }

    // merge: cross-lane over ml, then cross-wave via LDS
    #pragma unroll
    for (int k = 0; k < 8; ++k) {
        #pragma unroll
        for (int m = 1; m < 16; m <<= 1)
            b1[k] = fminf(b1[k], __shfl_xor(b1[k], m));
    }
    __syncthreads();
    if (ml == 0) {
        #pragma unroll
        for (int ti = 0; ti < 2; ++ti)
            #pragma unroll
            for (int r = 0; r < 4; ++r)
                d1buf[w * 32 + ti * 16 + q * 4 + r] = b1[ti * 4 + r];
    }
    __syncthreads();
    if (tid < 32) {
        float d = fminf(fminf(d1buf[tid], d1buf[32 + tid]),
                        fminf(d1buf[64 + tid], d1buf[96 + tid]));
        limitS[tid] = d + THR;
        pcnts[tid] = 0;
    }
    __syncthreads();
    float limit[8];
    #pragma unroll
    for (int ti = 0; ti < 2; ++ti)
        #pragma unroll
        for (int r = 0; r < 4; ++r)
            limit[ti * 4 + r] = limitS[ti * 16 + q * 4 + r];
    __syncthreads();

    // ---------------- pass 2: identical recompute + emit ----------------
    #pragma unroll
    for (int i = 0; i < 4; ++i) {
        int el = i * 256 + tid;
        int row = el >> 2, j = el & 3;
        int jsrc = j ^ ((row >> 1) & 3);
        gl_lds16(ehc + (size_t)row * 256 + jsrc * 8, sB0 + el * 16);
    }
    #pragma unroll 1
    for (int c = 0; c < nch; ++c) {
        float etb[4];
        #pragma unroll
        for (int tj = 0; tj < 4; ++tj) etb[tj] = ce2[c * 256 + wn0 + tj * 16 + ml];
        f32x4 acc[2][4];
        #pragma unroll
        for (int ti = 0; ti < 2; ++ti)
            #pragma unroll
            for (int tj = 0; tj < 4; ++tj)
                acc[ti][tj] = (f32x4){etb[tj], etb[tj], etb[tj], etb[tj]};
        #pragma unroll
        for (int s = 0; s < 8; ++s) {
            __syncthreads();
            if (s < 7 || c + 1 < nch) {
                int s2 = (s + 1) & 7;
                int cc2 = (s == 7) ? (c + 1) : c;
                char* dst = (s & 1) ? sB0 : sB1;
                #pragma unroll
                for (int i = 0; i < 4; ++i) {
                    int el = i * 256 + tid;
                    int row = el >> 2, j = el & 3;
                    int jsrc = j ^ ((row >> 1) & 3);
                    gl_lds16(ehc + (size_t)(cc2 * 256 + row) * 256 + s2 * 32 + jsrc * 8,
                             dst + el * 16);
                }
            }
            __builtin_amdgcn_sched_barrier(0);
            const char* sB = (s & 1) ? sB1 : sB0;
            half8 A[2], B[4];
            #pragma unroll
            for (int tj = 0; tj < 4; ++tj)
                B[tj] = *(const half8*)(sB + (wn0 + tj * 16 + ml) * 64 + slB * 16);
            int slotA = (s >> 1) * 8 + ((((s & 1) * 4) + q) ^ x7);
            #pragma unroll
            for (int ti = 0; ti < 2; ++ti)
                A[ti] = *(const half8*)(sAb + (ti * 16 + ml) * 512 + slotA * 16);
            #pragma unroll
            for (int ti = 0; ti < 2; ++ti)
                #pragma unroll
                for (int tj = 0; tj < 4; ++tj)
                    acc[ti][tj] = __builtin_amdgcn_mfma_f32_16x16x32_f16(A[ti], B[tj], acc[ti][tj], 0, 0, 0);
        }
        int slot0 = c * 256 + wn0 + ml;
        #pragma unroll
        for (int ti = 0; ti < 2; ++ti) {
            #pragma unroll
            for (int r = 0; r < 4; ++r) {
                int k = ti * 4 + r;
                int row = ti * 16 + q * 4 + r;
                #pragma unroll
                for (int tj = 0; tj < 4; ++tj) {
                    if (acc[ti][tj][r] <= limit[k]) {
                        int pos = atomicAdd(&pcnts[row], 1);
                        if (pos < 8) pls[row * 8 + pos] = slot0 + tj * 16;
                    }
                }
            }
        }
    }
    __syncthreads();
    // finalize: pc==1 -> bestn; pc>=2 -> enqueue
    if (tid < 32) {
        int t = t0 + tid;
        int pc = pcnts[tid];
        if (pc == 1) {
            bestn[t] = candIdx[pls[tid * 8]];
        } else {
            int pos = atomicAdd(cnt, 1);
            list2[pos] = t;
            pcnt[t] = pc;
            int mm = pc < 8 ? pc : 8;
            for (int i = 0; i < mm; ++i) plist[t * 8 + i] = pls[tid * 8 + i];
        }
    }
}

// ---------------- K8: exact fp32 eval of queued tokens, one wave each ----------------
__global__ void k_exact(const float* __restrict__ z, const float* __restrict__ emb,
                        const float* __restrict__ e2, const float* __restrict__ cst,
                        const int* __restrict__ cnt, const int* __restrict__ pcnt,
                        const int* __restrict__ plist, const int* __restrict__ candIdx,
                        const int* __restrict__ list2, int* __restrict__ bestn) {
    int w = threadIdx.x >> 6, lane = threadIdx.x & 63;
    int wid = blockIdx.x * 4 + w;              // grid 256 -> 1024 waves
    int NQ = cnt[0], C = cnt[1];
    float inv_s = cst[1];
    for (int it = wid; it < NQ; it += 1024) {
        int t = list2[it];
        int b = t >> 10, hw = t & 1023;
        const float* zb = z + (size_t)b * 262144 + hw;
        float4 a4;
        a4.x = zb[(size_t)(lane * 4 + 0) << 10] * (1.0f / 30.0f);
        a4.y = zb[(size_t)(lane * 4 + 1) << 10] * (1.0f / 30.0f);
        a4.z = zb[(size_t)(lane * 4 + 2) << 10] * (1.0f / 30.0f);
        a4.w = zb[(size_t)(lane * 4 + 3) << 10] * (1.0f / 30.0f);
        int pc = pcnt[t];
        float bestv = 3.4e38f; int bi = 0x7fffffff;
        if (pc <= 8) {
            for (int i = 0; i < pc; ++i) {
                int n = candIdx[plist[t * 8 + i]];
                float4 e4 = *(const float4*)&emb[(size_t)n * 256 + lane * 4];
                float s = a4.x * e4.x + a4.y * e4.y + a4.z * e4.z + a4.w * e4.w;
                #pragma unroll
                for (int m = 1; m < 64; m <<= 1) s += __shfl_xor(s, m);
                float d = fmaf(-2.0f, s, e2[n] * inv_s);
                if (d < bestv || (d == bestv && n < bi)) { bestv = d; bi = n; }
            }
        } else {
            for (int slot = 0; slot < C; ++slot) {
                int n = candIdx[slot];
                float4 e4 = *(const float4*)&emb[(size_t)n * 256 + lane * 4];
                float s = a4.x * e4.x + a4.y * e4.y + a4.z * e4.z + a4.w * e4.w;
                #pragma unroll
                for (int m = 1; m < 64; m <<= 1) s += __shfl_xor(s, m);
                float d = fmaf(-2.0f, s, e2[n] * inv_s);
                if (d < bestv || (d == bestv && n < bi)) { bestv = d; bi = n; }
            }
        }
        if (lane == 0) bestn[t] = bi;
    }
}

// ---------------- K9: emit z_q, idx, diff partials ----------------
__global__ void k_emit(const float* __restrict__ z, const float* __restrict__ emb,
                       const float* __restrict__ cst, const int* __restrict__ bestn,
                       float* __restrict__ out, float* __restrict__ diff_part) {
    int blk = blockIdx.x;                 // 256
    int cq = blk >> 6, sub = blk & 63;
    int b = sub >> 2;
    int tl = (sub & 3) * 256 + threadIdx.x;
    int t = b * 1024 + tl;
    int bi = bestn[t];
    if (cq == 0) out[4194305 + t] = (float)bi;
    float scale = cst[0];
    const float* er = emb + (size_t)bi * 256 + cq * 64;
    const float* zr = z + (size_t)b * 262144 + (size_t)cq * 65536 + tl;
    float* orow = out + (size_t)b * 262144 + (size_t)cq * 65536 + tl;
    float ds = 0.f;
    #pragma unroll 8
    for (int j = 0; j < 64; ++j) {
        float qv = er[j] * FIXLEN;
        float zt = zr[(size_t)j << 10] * scale;
        float dd = qv - zt;
        ds = fmaf(dd, dd, ds);
        orow[(size_t)j << 10] = qv;
    }
    __shared__ float red[256];
    red[threadIdx.x] = ds;
    __syncthreads();
    for (int off = 128; off > 0; off >>= 1) {
        if (threadIdx.x < off) red[threadIdx.x] += red[threadIdx.x + off];
        __syncthreads();
    }
    if (threadIdx.x == 0) diff_part[blk] = red[0];
}

// ---------------- K10: finalize diff ----------------
__global__ void k_diff(const float* __restrict__ diff_part, float* __restrict__ out) {
    int tid = threadIdx.x;   // 256
    __shared__ float red[256];
    red[tid] = diff_part[tid];
    __syncthreads();
    for (int off = 128; off > 0; off >>= 1) {
        if (tid < off) red[tid] += red[tid + off];
        __syncthreads();
    }
    if (tid == 0) out[4194304] = BETA * red[0] / 4194304.0f;
}

extern "C" void kernel_launch(void* const* d_in, const int* in_sizes, int n_in,
                              void* d_out, int out_size, void* d_ws, size_t ws_size,
                              hipStream_t stream) {
    const float* z   = (const float*)d_in[0];
    const float* emb = (const float*)d_in[1];
    float* out = (float*)d_out;
    char* wsb = (char*)d_ws;

    float* nrm_part  = (float*)(wsb + NRM_OFF);
    float* nrmx_part = (float*)(wsb + NRMX_OFF);
    float* cst       = (float*)(wsb + CST_OFF);
    int*   cnt       = (int*)(wsb + CNT_OFF);
    float* diff_part = (float*)(wsb + DIFF_OFF);
    float* zmax_part = (float*)(wsb + ZMAX_OFF);
    float* emaxl     = (float*)(wsb + EMAXL_OFF);
    float* emaxe     = (float*)(wsb + EMAXE_OFF);
    float* e2        = (float*)(wsb + E2_OFF);
    int*   bestn     = (int*)(wsb + BESTN_OFF);
    int*   pcnt      = (int*)(wsb + PCNT_OFF);
    int*   plist     = (int*)(wsb + PLIST_OFF);
    int*   candIdx   = (int*)(wsb + CIDX_OFF);
    float* ce2       = (float*)(wsb + CE2_OFF);
    int*   list2     = (int*)(wsb + LIST2_OFF);
    float* e2minp    = (float*)(wsb + E2MIN_OFF);
    float* zsumP     = (float*)(wsb + ZS_OFF);
    u16*   zh        = (u16*)(wsb + ZH_OFF);
    u16*   ehc       = (u16*)(wsb + EHC_OFF);

    k_split_e<<<2048, 256, 0, stream>>>(emb, e2, emaxl, emaxe, e2minp);
    k_split_z<<<1024, 256, 0, stream>>>(z, zh, zmax_part, zsumP);
    k_norm2<<<64, 256, 0, stream>>>(zsumP, nrm_part, nrmx_part);
    k_scalars<<<1, 256, 0, stream>>>(nrm_part, nrmx_part, zmax_part, emaxl, emaxe, e2minp, cst, cnt);
    k_select<<<64, 256, 0, stream>>>(e2, cst, candIdx, cnt);
    k_gather<<<64, 256, 0, stream>>>(emb, e2, cst, cnt, candIdx, ehc, ce2);
    k_cmfma<<<512, 256, 0, stream>>>(zh, ehc, ce2, cst, cnt, candIdx, pcnt, plist, list2, bestn);
    k_exact<<<256, 256, 0, stream>>>(z, emb, e2, cst, cnt, pcnt, plist, candIdx, list2, bestn);
    k_emit<<<256, 256, 0, stream>>>(z, emb, cst, bestn, out, diff_part);
    k_diff<<<1, 256, 0, stream>>>(diff_part, out);
}

// Round 10
// 156.393 us; speedup vs baseline: 2.8778x; 1.0037x over previous
//
#include <hip/hip_runtime.h>
#include <hip/hip_fp16.h>
#include <math.h>

#define FIXLEN 30.0f
#define BETA   0.25f

typedef unsigned short u16;
typedef unsigned int   u32;
typedef unsigned long long u64;
typedef _Float16 half8 __attribute__((ext_vector_type(8)));
typedef float    f32x4 __attribute__((ext_vector_type(4)));

// ---------------- ws layout (bytes) ----------------
#define NRM_OFF    0         // f[64] per-block norm-sum partials
#define NRMX_OFF   256       // f[64] per-block norm-max partials
#define CST_OFF    512       // f[16]: 0=scale,1=inv_s,2=EPS2,3=maxNrm,4=T_cut,6=diff acc
#define CNT_OFF    576       // i[4]: 0=queue cnt, 1=cand cnt, 2=nscalars ticket, 3=emit ticket
#define ZMAX_OFF   2048      // f[1024]
#define EMAXL_OFF  6144      // f[2048]
#define EMAXE_OFF  14336     // f[2048]
#define E2_OFF     22528     // f[16384] -> 88064
#define BESTN_OFF  88064     // i[16384] -> 153600
#define PCNT_OFF   153600    // i[16384] -> 219136
#define PLIST_OFF  219136    // i[16384*8] -> 743424
#define CIDX_OFF   743424    // i[16384] -> 808960
#define CE2_OFF    808960    // f[16384] -> 874496
#define LIST2_OFF  874496    // i[16384] queue of pc>=2 tokens -> 940032
#define E2MIN_OFF  940032    // f[2048] per-block e2-min partials -> 948224
#define ZS_OFF     1048576   // f[4*16384] z^2 partials -> 1310720
#define ZH_OFF     1792000   // half[16384*256] -> 10180608
#define EHC_OFF    10180608  // half[16384*256] gathered candidate plane -> 18569216

__device__ inline void gl_lds16(const void* g, void* l) {
    __builtin_amdgcn_global_load_lds(
        (const __attribute__((address_space(1))) unsigned int*)g,
        (__attribute__((address_space(3))) unsigned int*)l, 16, 0, 0);
}

// ---------------- K1: emb -> e2 + residual-norm maxes + e2-min partials + init tickets/ce2 ----
__global__ void k_split_e(const float* __restrict__ emb, float* __restrict__ e2,
                          float* __restrict__ emaxl, float* __restrict__ emaxe,
                          float* __restrict__ e2minp, float* __restrict__ ce2,
                          float* __restrict__ cst, int* __restrict__ cnt) {
    int gidx = blockIdx.x * 256 + threadIdx.x;   // grid = 2048
    int n = gidx >> 5;
    int c8 = (gidx & 31) * 8;
    if (gidx == 0) { cnt[2] = 0; cnt[3] = 0; cst[6] = 0.f; }
    if ((threadIdx.x & 31) == 0) ce2[n] = 3.0e37f;   // pad default: never near the min
    const float* ep = emb + (size_t)n * 256 + c8;
    float4 v0 = *(const float4*)ep;
    float4 v1 = *(const float4*)(ep + 4);
    float vv[8] = {v0.x, v0.y, v0.z, v0.w, v1.x, v1.y, v1.z, v1.w};
    float s2 = 0.f, r2 = 0.f;
    #pragma unroll
    for (int k = 0; k < 8; ++k) {
        __half h = __float2half(vv[k]);
        float r = vv[k] - __half2float(h);
        s2 = fmaf(vv[k], vv[k], s2);
        r2 = fmaf(r, r, r2);
    }
    #pragma unroll
    for (int off = 16; off > 0; off >>= 1) {
        s2 += __shfl_down(s2, off, 32);
        r2 += __shfl_down(r2, off, 32);
    }
    __shared__ float L1[8], L2[8];
    if ((threadIdx.x & 31) == 0) {
        e2[n] = s2;
        L1[threadIdx.x >> 5] = r2;
        L2[threadIdx.x >> 5] = s2;
    }
    __syncthreads();
    if (threadIdx.x == 0) {
        float a = 0.f, bmax = 0.f, bmin = 3.4e38f;
        #pragma unroll
        for (int i = 0; i < 8; ++i) {
            a = fmaxf(a, L1[i]);
            bmax = fmaxf(bmax, L2[i]);
            bmin = fminf(bmin, L2[i]);
        }
        emaxl[blockIdx.x] = a;
        emaxe[blockIdx.x] = bmax;
        e2minp[blockIdx.x] = bmin;
    }
}

// ---------------- K2: z -> fp16(-2*z/30) plane (transpose) + residual max + z^2 partials ------
__global__ void k_split_z(const float* __restrict__ z, u16* __restrict__ zh,
                          float* __restrict__ zmax_part, float* __restrict__ zsumP) {
    int bi = blockIdx.x;                     // grid = 1024
    int b = bi >> 6, rest = bi & 63;
    int c0 = (rest >> 4) * 64, s0 = (rest & 15) * 64;
    __shared__ float ld[64][65];
    __shared__ float red2[64][4];
    __shared__ float redz[64][4];
    __shared__ float rmax[64];
    int tid = threadIdx.x;
    #pragma unroll
    for (int p = 0; p < 16; ++p) {
        int idx = p * 256 + tid;
        int cc = idx >> 6, ss = idx & 63;
        ld[cc][ss] = z[(size_t)b * 262144 + (size_t)(c0 + cc) * 1024 + s0 + ss];
    }
    __syncthreads();
    int ss2 = tid >> 2, cq = tid & 3;
    int t = b * 1024 + s0 + ss2;
    float r2 = 0.f, zacc = 0.f;
    u32 pk[8];
    #pragma unroll
    for (int k = 0; k < 8; ++k) pk[k] = 0;
    #pragma unroll
    for (int j = 0; j < 16; ++j) {
        float raw = ld[cq * 16 + j][ss2];
        zacc = fmaf(raw, raw, zacc);
        float v = raw * (1.0f / 30.0f);
        __half h = __float2half(v);
        float vh = __half2float(h);
        float r = v - vh;
        r2 = fmaf(r, r, r2);
        __half hs = __float2half(-2.0f * vh);   // exact power-of-2 scale
        pk[j >> 1] |= ((u32)__half_as_ushort(hs)) << ((j & 1) * 16);
    }
    u16* dst = zh + (size_t)t * 256 + c0 + cq * 16;
    *(uint4*)dst = make_uint4(pk[0], pk[1], pk[2], pk[3]);
    *(uint4*)(dst + 8) = make_uint4(pk[4], pk[5], pk[6], pk[7]);
    red2[ss2][cq] = r2;
    redz[ss2][cq] = zacc;
    __syncthreads();
    if (tid < 64) {
        rmax[tid] = red2[tid][0] + red2[tid][1] + red2[tid][2] + red2[tid][3];
        zsumP[(size_t)(rest >> 4) * 16384 + b * 1024 + s0 + tid] =
            redz[tid][0] + redz[tid][1] + redz[tid][2] + redz[tid][3];
    }
    __syncthreads();
    for (int off = 32; off > 0; off >>= 1) {
        if (tid < off) rmax[tid] = fmaxf(rmax[tid], rmax[tid + off]);
        __syncthreads();
    }
    if (tid == 0) zmax_part[bi] = rmax[0];
}

// ---------------- K3: norm partials (grid 64) + last-block scalar finalize --------------------
// T = min_n UB(n); UB(e2) = e2*inv_s + 2*maxA*sqrt(e2) is increasing in e2 -> T = UB(e2min).
// +1.0 margin covers all fp32 evaluation differences.
__global__ void k_nscalars(const float* __restrict__ zsumP, const float* __restrict__ zmax_part,
                           const float* __restrict__ emaxl, const float* __restrict__ emaxe,
                           const float* __restrict__ e2minp, float* __restrict__ nrm_part,
                           float* __restrict__ nrmx_part, float* __restrict__ cst,
                           int* __restrict__ cnt) {
    int tid = threadIdx.x;
    int t = blockIdx.x * 256 + tid;   // grid = 64
    float tot = zsumP[t] + zsumP[16384 + t] + zsumP[32768 + t] + zsumP[49152 + t];
    float nrm = sqrtf(tot);
    __shared__ float rs[256], rm[256];
    rs[tid] = nrm; rm[tid] = nrm;
    __syncthreads();
    for (int off = 128; off > 0; off >>= 1) {
        if (tid < off) {
            rs[tid] += rs[tid + off];
            rm[tid] = fmaxf(rm[tid], rm[tid + off]);
        }
        __syncthreads();
    }
    __shared__ int amLast;
    if (tid == 0) {
        nrm_part[blockIdx.x] = rs[0];
        nrmx_part[blockIdx.x] = rm[0];
        __threadfence();
        amLast = (atomicAdd(&cnt[2], 1) == 63);
    }
    __syncthreads();
    if (!amLast) return;
    __threadfence();
    // ---- scalar finalize (last block only) ----
    float s = (tid < 64) ? nrm_part[tid] : 0.f;
    float m = (tid < 64) ? nrmx_part[tid] : 0.f;
    float zm = 0.f, el = 0.f, ee = 0.f, em = 3.4e38f;
    for (int i = tid; i < 1024; i += 256) zm = fmaxf(zm, zmax_part[i]);
    for (int i = tid; i < 2048; i += 256) {
        el = fmaxf(el, emaxl[i]);
        ee = fmaxf(ee, emaxe[i]);
        em = fminf(em, e2minp[i]);
    }
    __shared__ float S[256], M[256], Z[256], L[256], E[256], Q[256];
    S[tid] = s; M[tid] = m; Z[tid] = zm; L[tid] = el; E[tid] = ee; Q[tid] = em;
    __syncthreads();
    for (int off = 128; off > 0; off >>= 1) {
        if (tid < off) {
            S[tid] += S[tid + off];
            M[tid] = fmaxf(M[tid], M[tid + off]);
            Z[tid] = fmaxf(Z[tid], Z[tid + off]);
            L[tid] = fmaxf(L[tid], L[tid + off]);
            E[tid] = fmaxf(E[tid], E[tid + off]);
            Q[tid] = fminf(Q[tid], Q[tid + off]);
        }
        __syncthreads();
    }
    if (tid == 0) {
        float pre_len = S[0] * (1.0f / 16384.0f);
        float scale = (pre_len >= FIXLEN) ? (FIXLEN / pre_len) : 1.0f;
        float inv_s = 1.0f / scale;
        cst[0] = scale;
        cst[1] = inv_s;
        cst[3] = M[0];
        float maxA  = M[0] * (1.0f / 30.0f);
        float maxEl = sqrtf(L[0]);
        float maxE  = sqrtf(E[0]);
        float maxZl = 2.0f * sqrtf(Z[0]);
        float eps = 2.0f * (maxA * maxEl + maxZl * maxE + maxZl * maxEl) + 0.03f;
        float EPS2 = 2.0f * eps;
        cst[2] = EPS2;
        float e2min = Q[0];
        float T = fmaf(2.0f * maxA, sqrtf(e2min), e2min * inv_s);
        cst[4] = T + 2.0f * EPS2 + 1.0f;   // T_cut
        cnt[0] = 0;
        cnt[1] = 0;
    }
}

// ---------------- K4: fused select + gather (grid 64) ----------------
// Block-local LDS compaction (one global atomic per block), then cooperative row gather
// (8 rows x 32 threads).  ce2 pad slots pre-set to 3e37 in k_split_e; pad ehc rows are
// stale/NaN-safe: 3e37 bias + fminf/<= semantics keep them out of every min and emission.
__global__ void k_selgather(const float* __restrict__ emb, const float* __restrict__ e2,
                            const float* __restrict__ cst, int* __restrict__ candIdx,
                            int* __restrict__ cnt, u16* __restrict__ ehc,
                            float* __restrict__ ce2) {
    __shared__ int localN[256];
    __shared__ int lc, baseS;
    int tid = threadIdx.x;
    int n = blockIdx.x * 256 + tid;   // grid 64
    if (tid == 0) lc = 0;
    __syncthreads();
    float inv_s = cst[1], maxA = cst[3] * (1.0f / 30.0f), Tc = cst[4];
    float v = e2[n];
    float lb = fmaf(-2.0f * maxA, sqrtf(v), v * inv_s);
    int myPos = -1;
    if (lb <= Tc) myPos = atomicAdd(&lc, 1);
    __syncthreads();
    if (tid == 0) baseS = atomicAdd(cnt + 1, lc);
    __syncthreads();
    int L = lc, base = baseS;
    if (myPos >= 0) {
        localN[myPos] = n;
        candIdx[base + myPos] = n;
        ce2[base + myPos] = v * inv_s;
    }
    __syncthreads();
    for (int i0 = 0; i0 < L; i0 += 8) {
        int r = i0 + (tid >> 5);
        if (r < L) {
            int nn = localN[r];
            int c8 = (tid & 31) * 8;
            const float* ep = emb + (size_t)nn * 256 + c8;
            float4 v0 = *(const float4*)ep;
            float4 v1 = *(const float4*)(ep + 4);
            u32 p0 = (u32)__half_as_ushort(__float2half(v0.x)) |
                     ((u32)__half_as_ushort(__float2half(v0.y)) << 16);
            u32 p1 = (u32)__half_as_ushort(__float2half(v0.z)) |
                     ((u32)__half_as_ushort(__float2half(v0.w)) << 16);
            u32 p2 = (u32)__half_as_ushort(__float2half(v1.x)) |
                     ((u32)__half_as_ushort(__float2half(v1.y)) << 16);
            u32 p3 = (u32)__half_as_ushort(__float2half(v1.z)) |
                     ((u32)__half_as_ushort(__float2half(v1.w)) << 16);
            *(uint4*)&ehc[(size_t)(base + r) * 256 + c8] = make_uint4(p0, p1, p2, p3);
        }
    }
}

// ---------------- K5: candidate GEMM, 32 tok/block, two-pass, LDS pair lists ------------------
__launch_bounds__(256, 2)
__global__ void k_cmfma(const u16* __restrict__ zh, const u16* __restrict__ ehc,
                        const float* __restrict__ ce2, const float* __restrict__ cst,
                        int* __restrict__ cnt, const int* __restrict__ candIdx,
                        int* __restrict__ pcnt, int* __restrict__ plist,
                        int* __restrict__ list2, int* __restrict__ bestn) {
    __shared__ __align__(16) char lds[51200];
    char* sAb = lds;                        // 16 KB: [32 rows][32 slots16], slot^=(row&7) low3
    char* sB0 = lds + 16384;                // 16 KB: [256 rows][4 slots16], slot^=((row>>1)&3)
    char* sB1 = lds + 32768;                // 16 KB
    float* d1buf  = (float*)(lds + 49152);  // [4][32]
    float* limitS = (float*)(lds + 49664);  // [32]
    int*   pcnts  = (int*)(lds + 49792);    // [32]
    int*   pls    = (int*)(lds + 49920);    // [32][8]

    int t0 = blockIdx.x * 32;               // grid = 512
    int C = cnt[1];
    int nch = (C + 255) >> 8;
    float THR = cst[2] + 0.0625f;           // EPS2 + slack (extra emission is always sound)
    int tid = threadIdx.x, w = tid >> 6, lane = tid & 63;
    int ml = lane & 15, q = lane >> 4;
    int wn0 = w * 64;
    int x7 = ml & 7;
    int xb = (ml >> 1) & 3;
    int slB = q ^ xb;

    // prologue: stage A plane (4 granules/thread), source-XOR swizzle
    #pragma unroll
    for (int i = 0; i < 4; ++i) {
        int el = i * 256 + tid;
        int row = el >> 5, j = el & 31;
        int jsrc = (j & 24) | ((j & 7) ^ (row & 7));
        gl_lds16(zh + (size_t)(t0 + row) * 256 + jsrc * 8, sAb + el * 16);
    }
    // prologue: stage B chunk0 slice0 -> sB0 (4 granules/thread)
    #pragma unroll
    for (int i = 0; i < 4; ++i) {
        int el = i * 256 + tid;
        int row = el >> 2, j = el & 3;
        int jsrc = j ^ ((row >> 1) & 3);
        gl_lds16(ehc + (size_t)row * 256 + jsrc * 8, sB0 + el * 16);
    }

    float b1[8];
    #pragma unroll
    for (int k = 0; k < 8; ++k) b1[k] = 3.4e38f;

    // ---------------- pass 1: per-token min ----------------
    #pragma unroll 1
    for (int c = 0; c < nch; ++c) {
        float etb[4];
        #pragma unroll
        for (int tj = 0; tj < 4; ++tj) etb[tj] = ce2[c * 256 + wn0 + tj * 16 + ml];
        f32x4 acc[2][4];
        #pragma unroll
        for (int ti = 0; ti < 2; ++ti)
            #pragma unroll
            for (int tj = 0; tj < 4; ++tj)
                acc[ti][tj] = (f32x4){etb[tj], etb[tj], etb[tj], etb[tj]};
        #pragma unroll
        for (int s = 0; s < 8; ++s) {
            __syncthreads();
            if (s < 7 || c + 1 < nch) {
                int s2 = (s + 1) & 7;
                int cc2 = (s == 7) ? (c + 1) : c;
                char* dst = (s & 1) ? sB0 : sB1;
                #pragma unroll
                for (int i = 0; i < 4; ++i) {
                    int el = i * 256 + tid;
                    int row = el >> 2, j = el & 3;
                    int jsrc = j ^ ((row >> 1) & 3);
                    gl_lds16(ehc + (size_t)(cc2 * 256 + row) * 256 + s2 * 32 + jsrc * 8,
                             dst + el * 16);
                }
            }
            __builtin_amdgcn_sched_barrier(0);
            const char* sB = (s & 1) ? sB1 : sB0;
            half8 A[2], B[4];
            #pragma unroll
            for (int tj = 0; tj < 4; ++tj)
                B[tj] = *(const half8*)(sB + (wn0 + tj * 16 + ml) * 64 + slB * 16);
            int slotA = (s >> 1) * 8 + ((((s & 1) * 4) + q) ^ x7);
            #pragma unroll
            for (int ti = 0; ti < 2; ++ti)
                A[ti] = *(const half8*)(sAb + (ti * 16 + ml) * 512 + slotA * 16);
            #pragma unroll
            for (int ti = 0; ti < 2; ++ti)
                #pragma unroll
                for (int tj = 0; tj < 4; ++tj)
                    acc[ti][tj] = __builtin_amdgcn_mfma_f32_16x16x32_f16(A[ti], B[tj], acc[ti][tj], 0, 0, 0);
        }
        #pragma unroll
        for (int ti = 0; ti < 2; ++ti)
            #pragma unroll
            for (int r = 0; r < 4; ++r)
                #pragma unroll
                for (int tj = 0; tj < 4; ++tj)
                    b1[ti * 4 + r] = fminf(b1[ti * 4 + r], acc[ti][tj][r]);
    }

    // merge: cross-lane over ml, then cross-wave via LDS
    #pragma unroll
    for (int k = 0; k < 8; ++k) {
        #pragma unroll
        for (int m = 1; m < 16; m <<= 1)
            b1[k] = fminf(b1[k], __shfl_xor(b1[k], m));
    }
    __syncthreads();
    if (ml == 0) {
        #pragma unroll
        for (int ti = 0; ti < 2; ++ti)
            #pragma unroll
            for (int r = 0; r < 4; ++r)
                d1buf[w * 32 + ti * 16 + q * 4 + r] = b1[ti * 4 + r];
    }
    __syncthreads();
    if (tid < 32) {
        float d = fminf(fminf(d1buf[tid], d1buf[32 + tid]),
                        fminf(d1buf[64 + tid], d1buf[96 + tid]));
        limitS[tid] = d + THR;
        pcnts[tid] = 0;
    }
    __syncthreads();
    float limit[8];
    #pragma unroll
    for (int ti = 0; ti < 2; ++ti)
        #pragma unroll
        for (int r = 0; r < 4; ++r)
            limit[ti * 4 + r] = limitS[ti * 16 + q * 4 + r];
    __syncthreads();

    // ---------------- pass 2: identical recompute + emit ----------------
    #pragma unroll
    for (int i = 0; i < 4; ++i) {
        int el = i * 256 + tid;
        int row = el >> 2, j = el & 3;
        int jsrc = j ^ ((row >> 1) & 3);
        gl_lds16(ehc + (size_t)row * 256 + jsrc * 8, sB0 + el * 16);
    }
    #pragma unroll 1
    for (int c = 0; c < nch; ++c) {
        float etb[4];
        #pragma unroll
        for (int tj = 0; tj < 4; ++tj) etb[tj] = ce2[c * 256 + wn0 + tj * 16 + ml];
        f32x4 acc[2][4];
        #pragma unroll
        for (int ti = 0; ti < 2; ++ti)
            #pragma unroll
            for (int tj = 0; tj < 4; ++tj)
                acc[ti][tj] = (f32x4){etb[tj], etb[tj], etb[tj], etb[tj]};
        #pragma unroll
        for (int s = 0; s < 8; ++s) {
            __syncthreads();
            if (s < 7 || c + 1 < nch) {
                int s2 = (s + 1) & 7;
                int cc2 = (s == 7) ? (c + 1) : c;
                char* dst = (s & 1) ? sB0 : sB1;
                #pragma unroll
                for (int i = 0; i < 4; ++i) {
                    int el = i * 256 + tid;
                    int row = el >> 2, j = el & 3;
                    int jsrc = j ^ ((row >> 1) & 3);
                    gl_lds16(ehc + (size_t)(cc2 * 256 + row) * 256 + s2 * 32 + jsrc * 8,
                             dst + el * 16);
                }
            }
            __builtin_amdgcn_sched_barrier(0);
            const char* sB = (s & 1) ? sB1 : sB0;
            half8 A[2], B[4];
            #pragma unroll
            for (int tj = 0; tj < 4; ++tj)
                B[tj] = *(const half8*)(sB + (wn0 + tj * 16 + ml) * 64 + slB * 16);
            int slotA = (s >> 1) * 8 + ((((s & 1) * 4) + q) ^ x7);
            #pragma unroll
            for (int ti = 0; ti < 2; ++ti)
                A[ti] = *(const half8*)(sAb + (ti * 16 + ml) * 512 + slotA * 16);
            #pragma unroll
            for (int ti = 0; ti < 2; ++ti)
                #pragma unroll
                for (int tj = 0; tj < 4; ++tj)
                    acc[ti][tj] = __builtin_amdgcn_mfma_f32_16x16x32_f16(A[ti], B[tj], acc[ti][tj], 0, 0, 0);
        }
        int slot0 = c * 256 + wn0 + ml;
        #pragma unroll
        for (int ti = 0; ti < 2; ++ti) {
            #pragma unroll
            for (int r = 0; r < 4; ++r) {
                int k = ti * 4 + r;
                int row = ti * 16 + q * 4 + r;
                #pragma unroll
                for (int tj = 0; tj < 4; ++tj) {
                    if (acc[ti][tj][r] <= limit[k]) {
                        int pos = atomicAdd(&pcnts[row], 1);
                        if (pos < 8) pls[row * 8 + pos] = slot0 + tj * 16;
                    }
                }
            }
        }
    }
    __syncthreads();
    // finalize: pc==1 -> bestn; pc>=2 -> enqueue
    if (tid < 32) {
        int t = t0 + tid;
        int pc = pcnts[tid];
        if (pc == 1) {
            bestn[t] = candIdx[pls[tid * 8]];
        } else {
            int pos = atomicAdd(cnt, 1);
            list2[pos] = t;
            pcnt[t] = pc;
            int mm = pc < 8 ? pc : 8;
            for (int i = 0; i < mm; ++i) plist[t * 8 + i] = pls[tid * 8 + i];
        }
    }
}

// ---------------- K6: exact fp32 eval of queued tokens, one wave each ----------------
__global__ void k_exact(const float* __restrict__ z, const float* __restrict__ emb,
                        const float* __restrict__ e2, const float* __restrict__ cst,
                        const int* __restrict__ cnt, const int* __restrict__ pcnt,
                        const int* __restrict__ plist, const int* __restrict__ candIdx,
                        const int* __restrict__ list2, int* __restrict__ bestn) {
    int w = threadIdx.x >> 6, lane = threadIdx.x & 63;
    int wid = blockIdx.x * 4 + w;              // grid 256 -> 1024 waves
    int NQ = cnt[0], C = cnt[1];
    float inv_s = cst[1];
    for (int it = wid; it < NQ; it += 1024) {
        int t = list2[it];
        int b = t >> 10, hw = t & 1023;
        const float* zb = z + (size_t)b * 262144 + hw;
        float4 a4;
        a4.x = zb[(size_t)(lane * 4 + 0) << 10] * (1.0f / 30.0f);
        a4.y = zb[(size_t)(lane * 4 + 1) << 10] * (1.0f / 30.0f);
        a4.z = zb[(size_t)(lane * 4 + 2) << 10] * (1.0f / 30.0f);
        a4.w = zb[(size_t)(lane * 4 + 3) << 10] * (1.0f / 30.0f);
        int pc = pcnt[t];
        float bestv = 3.4e38f; int bi = 0x7fffffff;
        if (pc <= 8) {
            for (int i = 0; i < pc; ++i) {
                int n = candIdx[plist[t * 8 + i]];
                float4 e4 = *(const float4*)&emb[(size_t)n * 256 + lane * 4];
                float s = a4.x * e4.x + a4.y * e4.y + a4.z * e4.z + a4.w * e4.w;
                #pragma unroll
                for (int m = 1; m < 64; m <<= 1) s += __shfl_xor(s, m);
                float d = fmaf(-2.0f, s, e2[n] * inv_s);
                if (d < bestv || (d == bestv && n < bi)) { bestv = d; bi = n; }
            }
        } else {
            for (int slot = 0; slot < C; ++slot) {
                int n = candIdx[slot];
                float4 e4 = *(const float4*)&emb[(size_t)n * 256 + lane * 4];
                float s = a4.x * e4.x + a4.y * e4.y + a4.z * e4.z + a4.w * e4.w;
                #pragma unroll
                for (int m = 1; m < 64; m <<= 1) s += __shfl_xor(s, m);
                float d = fmaf(-2.0f, s, e2[n] * inv_s);
                if (d < bestv || (d == bestv && n < bi)) { bestv = d; bi = n; }
            }
        }
        if (lane == 0) bestn[t] = bi;
    }
}

// ---------------- K7: emit z_q, idx + fused diff finalize (last-block ticket) ----------------
__global__ void k_emit(const float* __restrict__ z, const float* __restrict__ emb,
                       float* __restrict__ cst, const int* __restrict__ bestn,
                       float* __restrict__ out, int* __restrict__ cnt) {
    int blk = blockIdx.x;                 // 256
    int cq = blk >> 6, sub = blk & 63;
    int b = sub >> 2;
    int tl = (sub & 3) * 256 + threadIdx.x;
    int t = b * 1024 + tl;
    int bi = bestn[t];
    if (cq == 0) out[4194305 + t] = (float)bi;
    float scale = cst[0];
    const float* er = emb + (size_t)bi * 256 + cq * 64;
    const float* zr = z + (size_t)b * 262144 + (size_t)cq * 65536 + tl;
    float* orow = out + (size_t)b * 262144 + (size_t)cq * 65536 + tl;
    float ds = 0.f;
    #pragma unroll 8
    for (int j = 0; j < 64; ++j) {
        float qv = er[j] * FIXLEN;
        float zt = zr[(size_t)j << 10] * scale;
        float dd = qv - zt;
        ds = fmaf(dd, dd, ds);
        orow[(size_t)j << 10] = qv;
    }
    __shared__ float red[256];
    red[threadIdx.x] = ds;
    __syncthreads();
    for (int off = 128; off > 0; off >>= 1) {
        if (threadIdx.x < off) red[threadIdx.x] += red[threadIdx.x + off];
        __syncthreads();
    }
    if (threadIdx.x == 0) {
        atomicAdd(&cst[6], red[0]);
        __threadfence();
        int tick = atomicAdd(&cnt[3], 1);
        if (tick == 255) {
            __threadfence();
            float total = atomicAdd(&cst[6], 0.0f);   // coherent read
            out[4194304] = BETA * total / 4194304.0f;
        }
    }
}

extern "C" void kernel_launch(void* const* d_in, const int* in_sizes, int n_in,
                              void* d_out, int out_size, void* d_ws, size_t ws_size,
                              hipStream_t stream) {
    const float* z   = (const float*)d_in[0];
    const float* emb = (const float*)d_in[1];
    float* out = (float*)d_out;
    char* wsb = (char*)d_ws;

    float* nrm_part  = (float*)(wsb + NRM_OFF);
    float* nrmx_part = (float*)(wsb + NRMX_OFF);
    float* cst       = (float*)(wsb + CST_OFF);
    int*   cnt       = (int*)(wsb + CNT_OFF);
    float* zmax_part = (float*)(wsb + ZMAX_OFF);
    float* emaxl     = (float*)(wsb + EMAXL_OFF);
    float* emaxe     = (float*)(wsb + EMAXE_OFF);
    float* e2        = (float*)(wsb + E2_OFF);
    int*   bestn     = (int*)(wsb + BESTN_OFF);
    int*   pcnt      = (int*)(wsb + PCNT_OFF);
    int*   plist     = (int*)(wsb + PLIST_OFF);
    int*   candIdx   = (int*)(wsb + CIDX_OFF);
    float* ce2       = (float*)(wsb + CE2_OFF);
    int*   list2     = (int*)(wsb + LIST2_OFF);
    float* e2minp    = (float*)(wsb + E2MIN_OFF);
    float* zsumP     = (float*)(wsb + ZS_OFF);
    u16*   zh        = (u16*)(wsb + ZH_OFF);
    u16*   ehc       = (u16*)(wsb + EHC_OFF);

    k_split_e<<<2048, 256, 0, stream>>>(emb, e2, emaxl, emaxe, e2minp, ce2, cst, cnt);
    k_split_z<<<1024, 256, 0, stream>>>(z, zh, zmax_part, zsumP);
    k_nscalars<<<64, 256, 0, stream>>>(zsumP, zmax_part, emaxl, emaxe, e2minp,
                                       nrm_part, nrmx_part, cst, cnt);
    k_selgather<<<64, 256, 0, stream>>>(emb, e2, cst, candIdx, cnt, ehc, ce2);
    k_cmfma<<<512, 256, 0, stream>>>(zh, ehc, ce2, cst, cnt, candIdx, pcnt, plist, list2, bestn);
    k_exact<<<256, 256, 0, stream>>>(z, emb, e2, cst, cnt, pcnt, plist, candIdx, list2, bestn);
    k_emit<<<256, 256, 0, stream>>>(z, emb, cst, bestn, out, cnt);
}